// Round 15
// baseline (729.587 us; speedup 1.0000x reference)
//
#include <hip/hip_runtime.h>
#include <math.h>

typedef short bf16x8 __attribute__((ext_vector_type(8)));
typedef float f32x4  __attribute__((ext_vector_type(4)));

__device__ __forceinline__ unsigned short f2bf(float x) {
    unsigned u = __float_as_uint(x);
    unsigned r = u + 0x7FFFu + ((u >> 16) & 1u);   // RNE
    return (unsigned short)(r >> 16);
}
__device__ __forceinline__ float bf2f(unsigned short b) {
    return __uint_as_float(((unsigned)b) << 16);
}

// ============ weight converts -> FRAGMENT-MAJOR layouts ============
// Layout D: chunk (kblk=k/32, cblk=c/64, n=c&3) holds 64 lanes x 8 elems;
//   lane = (c>>2)&15 | ((k>>3)&3)<<4 ; elem = k&7.
//   Kernel: bfr[n] = Wt[ ((kblk*ncb + cblk)*4 + n)*512 + lane*8 ]  (coalesced 1024B)
//   Epilogue: lane lr slot n = logical col (64-panel base) + 4*lr + n
__global__ __launch_bounds__(256)
void wconvD(const float* __restrict__ W, unsigned short* __restrict__ Wt, int K, int N)
{
    int id = blockIdx.x * 256 + threadIdx.x;
    if (id >= K * N) return;
    int c = id / K, k = id - c * K;
    int kblk = k >> 5, ksub = (k >> 3) & 3, kel = k & 7;
    int cblk = c >> 6, n = c & 3, lr = (c >> 2) & 15;
    int lane = lr + (ksub << 4);
    size_t dst = ((((size_t)kblk * (N >> 6) + cblk) * 4 + n) << 9) + (lane << 3) + kel;
    Wt[dst] = f2bf(W[(size_t)k * N + c]);
}

// Layout E (128-wide ep/tail): chunk (ks=k/32, n=c&7); lane = (c>>3)&15 | ((k>>3)&3)<<4.
// all seven 128x128 tail weights in one launch: Wg0,Wg1,Wemb,Wl0,Wl1,Wr0,Wr1
__global__ __launch_bounds__(256)
void wconv7(const float* __restrict__ Wg, const float* __restrict__ Wemb,
            const float* __restrict__ Wl, const float* __restrict__ Wr,
            unsigned short* __restrict__ dst)
{
    int id = blockIdx.x * 256 + threadIdx.x;    // < 7*16384
    if (id >= 7 * 16384) return;
    int m = id >> 14, r = id & 16383;
    int c = r >> 7, k = r & 127;
    const float* src = (m < 2) ? (Wg + m * 16384)
                     : (m == 2) ? Wemb
                     : (m < 5) ? (Wl + (m - 3) * 16384)
                               : (Wr + (m - 5) * 16384);
    int n = c & 7, lr = (c >> 3) & 15;
    int ks = k >> 5, ksub = (k >> 3) & 3, kel = k & 7;
    int lane = lr + (ksub << 4);
    dst[(size_t)m * 16384 + (((ks << 3) + n) << 9) + (lane << 3) + kel] = f2bf(src[(size_t)k * 128 + c]);
}

// ============ bulk f32 -> bf16 ============
__global__ __launch_bounds__(256)
void f32_to_bf16(const float* __restrict__ in, unsigned short* __restrict__ outb, long n8)
{
    long id = (long)blockIdx.x * 256 + threadIdx.x;
    if (id >= n8) return;
    const float4* p = (const float4*)(in + id * 8);
    float4 a = p[0], b = p[1];
    *(ushort4*)(outb + id * 8)     = make_ushort4(f2bf(a.x), f2bf(a.y), f2bf(a.z), f2bf(a.w));
    *(ushort4*)(outb + id * 8 + 4) = make_ushort4(f2bf(b.x), f2bf(b.y), f2bf(b.z), f2bf(b.w));
}

// ============ fused head: x = tanh( tanh(feat@Wf0+bf0) @ Wf1 + bf1 ) ============
// 512 threads = 8 waves = 4 row-groups x 2 col-halves; block = 64 rows.
// Stage 1: wave (rg,ch) computes x1 rows rg*16.. x cols ch*128.. (acc 8 frags);
//   epilogue -> bf16 into shared x1s[rg]. One barrier. Stage 2: wave (rg,ch)
//   computes x rows rg*16.. x cols ch*64.. from LDS A-frags (acc 4 frags).
// Weights: Wt0 layout D (K=512,N=256), Wt1 layout D (K=256,N=128).
__global__ __launch_bounds__(512)
void mfma_head(const unsigned short* __restrict__ Ab, const unsigned short* __restrict__ Wt0,
               const float* __restrict__ bf0, const unsigned short* __restrict__ Wt1,
               const float* __restrict__ bf1, unsigned short* __restrict__ x_bf, int M)
{
    __shared__ __align__(16) unsigned short x1s[4][16][264];   // 33.8 KB

    const int tid  = threadIdx.x;
    const int wv   = tid >> 6, lane = tid & 63;
    const int rg   = wv >> 1, ch = wv & 1;
    const int lr   = lane & 15;
    const int lk8  = (lane >> 4) * 8;
    const int rbase = (lane >> 4) * 4;
    const int row0 = blockIdx.x * 64 + rg * 16;

    // ---- stage 1: 16 rows x 128 cols (panels ch*2, ch*2+1) ----
    const unsigned short* arow;
    { int r = row0 + lr; r = r < M ? r : (M - 1); arow = Ab + (size_t)r * 512 + lk8; }
    // layout D, ncb = 4 (N=256): chunk = (kblk*4 + cblk)*4 + n
    const unsigned short* bb0 = Wt0 + ((((size_t)ch * 2) * 4) << 9) + (lane << 3);

    f32x4 acc1[8];
#pragma unroll
    for (int s = 0; s < 8; s++)
#pragma unroll
        for (int q = 0; q < 4; q++) acc1[s][q] = 0.f;

#pragma unroll 2
    for (int kb = 0; kb < 16; kb++) {
        bf16x8 af = *(const bf16x8*)(arow + kb * 32);
        bf16x8 bn[8];
        const unsigned short* bk = bb0 + (((size_t)kb * 16) << 9);
#pragma unroll
        for (int s = 0; s < 8; s++) bn[s] = *(const bf16x8*)(bk + ((size_t)s << 9));
#pragma unroll
        for (int s = 0; s < 8; s++)
            acc1[s] = __builtin_amdgcn_mfma_f32_16x16x32_bf16(af, bn[s], acc1[s], 0, 0, 0);
    }

    // epilogue 1 -> LDS (bf16, same rounding as old x1_bf)
#pragma unroll
    for (int cb = 0; cb < 2; cb++) {
        int colp = (ch * 2 + cb) * 64 + lr * 4;
        float4 b4 = *(const float4*)(bf0 + colp);
        float bv[4] = {b4.x, b4.y, b4.z, b4.w};
#pragma unroll
        for (int j = 0; j < 4; j++) {
            ushort4 o;
            o.x = f2bf(tanhf(acc1[cb * 4 + 0][j] + bv[0]));
            o.y = f2bf(tanhf(acc1[cb * 4 + 1][j] + bv[1]));
            o.z = f2bf(tanhf(acc1[cb * 4 + 2][j] + bv[2]));
            o.w = f2bf(tanhf(acc1[cb * 4 + 3][j] + bv[3]));
            *(ushort4*)&x1s[rg][rbase + j][colp] = o;
        }
    }
    __syncthreads();

    // ---- stage 2: 16 rows x 64 cols (panel ch) from LDS A-frags ----
    // layout D, ncb = 2 (N=128): chunk = (ks*2 + ch)*4 + n
    const unsigned short* bb1 = Wt1 + ((((size_t)ch) * 4) << 9) + (lane << 3);

    f32x4 acc2[4];
#pragma unroll
    for (int n = 0; n < 4; n++)
#pragma unroll
        for (int q = 0; q < 4; q++) acc2[n][q] = 0.f;

#pragma unroll 2
    for (int ks = 0; ks < 8; ks++) {
        bf16x8 af = *(const bf16x8*)&x1s[rg][lr][ks * 32 + lk8];
        bf16x8 bn[4];
        const unsigned short* bk = bb1 + (((size_t)ks * 8) << 9);
#pragma unroll
        for (int n = 0; n < 4; n++) bn[n] = *(const bf16x8*)(bk + ((size_t)n << 9));
#pragma unroll
        for (int n = 0; n < 4; n++)
            acc2[n] = __builtin_amdgcn_mfma_f32_16x16x32_bf16(af, bn[n], acc2[n], 0, 0, 0);
    }

    const int cbase = ch * 64 + lr * 4;
    float4 b4 = *(const float4*)(bf1 + cbase);
    float bv[4] = {b4.x, b4.y, b4.z, b4.w};
#pragma unroll
    for (int j = 0; j < 4; j++) {
        int row = row0 + rbase + j;
        if (row < M) {
            ushort4 o;
            o.x = f2bf(tanhf(acc2[0][j] + bv[0]));
            o.y = f2bf(tanhf(acc2[1][j] + bv[1]));
            o.z = f2bf(tanhf(acc2[2][j] + bv[2]));
            o.w = f2bf(tanhf(acc2[3][j] + bv[3]));
            *(ushort4*)(x_bf + ((size_t)row << 7) + cbase) = o;
        }
    }
}

// ============ MFMA K=128 single-tile, fragment-major B, fused epilogue (s4) ============
template<bool ABF16, bool TANH, bool L2, bool RESID, bool AUX, bool AUXBF,
         bool F32OUT, bool BF16OUT, bool BIAS>
__global__ __launch_bounds__(256)
void mfma_ep(const void* __restrict__ A_, const unsigned short* __restrict__ Wt,
             const float* __restrict__ bias, const unsigned short* __restrict__ resid_bf,
             const void* __restrict__ aux_in, float* __restrict__ aux_out,
             float* __restrict__ out, unsigned short* __restrict__ out_bf, int M)
{
    const int tid  = threadIdx.x;
    const int row0 = blockIdx.x * 64;
    const int wv   = tid >> 6, lane = tid & 63;
    const int lr   = lane & 15;
    const int lk8  = (lane >> 4) * 8;
    const int wr   = wv * 16;

    const unsigned short* Abr;
    const float*          Afr;
    {
        int r = row0 + wr + lr;
        r = r < M ? r : (M - 1);
        Abr = (const unsigned short*)A_ + ((size_t)r << 7) + lk8;
        Afr = (const float*)A_          + ((size_t)r << 7) + lk8;
    }
    const unsigned short* wb = Wt + (lane << 3);

    f32x4 acc[8];
#pragma unroll
    for (int n = 0; n < 8; n++)
#pragma unroll
        for (int j = 0; j < 4; j++) acc[n][j] = 0.f;

#pragma unroll 2
    for (int ks = 0; ks < 4; ks++) {
        bf16x8 af, bn[8];
        if (ABF16) af = *(const bf16x8*)(Abr + ks * 32);
        else {
            float4 a = *(const float4*)(Afr + ks * 32);
            float4 b = *(const float4*)(Afr + ks * 32 + 4);
            af[0]=(short)f2bf(a.x); af[1]=(short)f2bf(a.y); af[2]=(short)f2bf(a.z); af[3]=(short)f2bf(a.w);
            af[4]=(short)f2bf(b.x); af[5]=(short)f2bf(b.y); af[6]=(short)f2bf(b.z); af[7]=(short)f2bf(b.w);
        }
#pragma unroll
        for (int n = 0; n < 8; n++)
            bn[n] = *(const bf16x8*)(wb + ((((ks << 3) + n)) << 9));
#pragma unroll
        for (int n = 0; n < 8; n++)
            acc[n] = __builtin_amdgcn_mfma_f32_16x16x32_bf16(af, bn[n], acc[n], 0, 0, 0);
    }

    const int cbase = lr * 8;
    float bv[8];
    if (BIAS) {
        float4 b0 = *(const float4*)(bias + cbase);
        float4 b1 = *(const float4*)(bias + cbase + 4);
        bv[0]=b0.x; bv[1]=b0.y; bv[2]=b0.z; bv[3]=b0.w;
        bv[4]=b1.x; bv[5]=b1.y; bv[6]=b1.z; bv[7]=b1.w;
    } else {
#pragma unroll
        for (int n = 0; n < 8; n++) bv[n] = 0.f;
    }
    const int rbase = (lane >> 4) * 4;

#pragma unroll
    for (int j = 0; j < 4; j++) {
        int row = row0 + wr + rbase + j;
        bool ok = row < M;
        size_t base = ((size_t)row << 7) + cbase;
        float v[8];
#pragma unroll
        for (int n = 0; n < 8; n++) {
            v[n] = acc[n][j] + bv[n];
            if (TANH) v[n] = tanhf(v[n]);
        }
        if (RESID) {
            if (ok) {
                bf16x8 rv = *(const bf16x8*)(resid_bf + base);
#pragma unroll
                for (int n = 0; n < 8; n++) v[n] += bf2f((unsigned short)rv[n]);
            }
        }
        if (L2) {
            float s = 0.f;
#pragma unroll
            for (int n = 0; n < 8; n++) s += v[n] * v[n];
#pragma unroll
            for (int msk = 8; msk >= 1; msk >>= 1) s += __shfl_xor(s, msk);
            float sc = 1.f / fmaxf(sqrtf(s), 1e-12f);
#pragma unroll
            for (int n = 0; n < 8; n++) v[n] *= sc;
        }
        if (ok) {
            if (F32OUT) {
                *(float4*)(out + base)     = make_float4(v[0], v[1], v[2], v[3]);
                *(float4*)(out + base + 4) = make_float4(v[4], v[5], v[6], v[7]);
            }
            if (BF16OUT) {
                bf16x8 o;
#pragma unroll
                for (int n = 0; n < 8; n++) o[n] = (short)f2bf(v[n]);
                *(bf16x8*)(out_bf + base) = o;
            }
            if (AUX) {
                float ai[8];
                if (AUXBF) {
                    bf16x8 av = *(const bf16x8*)((const unsigned short*)aux_in + base);
#pragma unroll
                    for (int n = 0; n < 8; n++) ai[n] = bf2f((unsigned short)av[n]);
                } else {
                    float4 a0 = *(const float4*)((const float*)aux_in + base);
                    float4 a1 = *(const float4*)((const float*)aux_in + base + 4);
                    ai[0]=a0.x; ai[1]=a0.y; ai[2]=a0.z; ai[3]=a0.w;
                    ai[4]=a1.x; ai[5]=a1.y; ai[6]=a1.z; ai[7]=a1.w;
                }
                *(float4*)(aux_out + base)     = make_float4(ai[0]+v[0], ai[1]+v[1], ai[2]+v[2], ai[3]+v[3]);
                *(float4*)(aux_out + base + 4) = make_float4(ai[4]+v[4], ai[5]+v[5], ai[6]+v[6], ai[7]+v[7]);
            }
        }
    }
}

// ============ fused tail (fragment-major weights) ============
__global__ __launch_bounds__(256)
void tail_fused(const unsigned short* __restrict__ h_bf, const float* __restrict__ accf,
                const unsigned short* __restrict__ Wt7,
                const float* __restrict__ bemb, const float* __restrict__ bl,
                const float* __restrict__ br,
                float* __restrict__ embO, float* __restrict__ lftO,
                float* __restrict__ rgtO, int M)
{
    __shared__ __align__(16) unsigned short ldsA[4][16][136];  // n1
    __shared__ __align__(16) unsigned short ldsB[4][16][136];  // acc / lft0 / rgt0

    const int tid = threadIdx.x;
    const int wv = tid >> 6, lane = tid & 63;
    const int lr = lane & 15;
    const int lk8 = (lane >> 4) * 8;
    const int rbase = (lane >> 4) * 4;
    const int row0 = blockIdx.x * 64 + wv * 16;
    const int cbase = lr * 8;

    const unsigned short* Wg1t  = Wt7 + 1 * 16384 + (lane << 3);
    const unsigned short* Wembt = Wt7 + 2 * 16384 + (lane << 3);
    const unsigned short* Wl0t  = Wt7 + 3 * 16384 + (lane << 3);
    const unsigned short* Wl1t  = Wt7 + 4 * 16384 + (lane << 3);
    const unsigned short* Wr0t  = Wt7 + 5 * 16384 + (lane << 3);
    const unsigned short* Wr1t  = Wt7 + 6 * 16384 + (lane << 3);

    f32x4 acc[8];

#define ZACC() { _Pragma("unroll") for (int n = 0; n < 8; n++) \
                 _Pragma("unroll") for (int q = 0; q < 4; q++) acc[n][q] = 0.f; }
#define MM128(AFRAG, WPTR)                                                            \
    _Pragma("unroll")                                                                 \
    for (int ks = 0; ks < 4; ks++) {                                                  \
        bf16x8 af = (AFRAG);                                                          \
        bf16x8 bn[8];                                                                 \
        _Pragma("unroll")                                                             \
        for (int n = 0; n < 8; n++)                                                   \
            bn[n] = *(const bf16x8*)((WPTR) + ((((ks << 3) + n)) << 9));              \
        _Pragma("unroll")                                                             \
        for (int n = 0; n < 8; n++)                                                   \
            acc[n] = __builtin_amdgcn_mfma_f32_16x16x32_bf16(af, bn[n], acc[n], 0, 0, 0); \
    }
#define LDBIAS(BV, P) { float4 b0_ = *(const float4*)((P) + cbase);                   \
                        float4 b1_ = *(const float4*)((P) + cbase + 4);               \
                        BV[0]=b0_.x; BV[1]=b0_.y; BV[2]=b0_.z; BV[3]=b0_.w;           \
                        BV[4]=b1_.x; BV[5]=b1_.y; BV[6]=b1_.z; BV[7]=b1_.w; }
#define L2NORM(V) { float s_ = 0.f;                                                   \
                    _Pragma("unroll") for (int n = 0; n < 8; n++) s_ += V[n]*V[n];    \
                    _Pragma("unroll") for (int mk = 8; mk >= 1; mk >>= 1) s_ += __shfl_xor(s_, mk); \
                    float sc_ = 1.f / fmaxf(sqrtf(s_), 1e-12f);                       \
                    _Pragma("unroll") for (int n = 0; n < 8; n++) V[n] *= sc_; }

    // ---- stage 1: n1 = l2norm(tanh(h @ Wg1)); acc = accf + n1 ----
    const unsigned short* hrow;
    {
        int r = row0 + lr;
        r = r < M ? r : (M - 1);
        hrow = h_bf + ((size_t)r << 7) + lk8;
    }
    ZACC();
    MM128(*(const bf16x8*)(hrow + ks * 32), Wg1t);
#pragma unroll
    for (int j = 0; j < 4; j++) {
        int row = row0 + rbase + j;
        int rc = row < M ? row : (M - 1);
        float v[8];
#pragma unroll
        for (int n = 0; n < 8; n++) v[n] = tanhf(acc[n][j]);
        L2NORM(v);
        bf16x8 o;
#pragma unroll
        for (int n = 0; n < 8; n++) o[n] = (short)f2bf(v[n]);
        *(bf16x8*)&ldsA[wv][rbase + j][cbase] = o;
        float4 a0 = *(const float4*)(accf + ((size_t)rc << 7) + cbase);
        float4 a1 = *(const float4*)(accf + ((size_t)rc << 7) + cbase + 4);
        float av[8] = {a0.x+v[0], a0.y+v[1], a0.z+v[2], a0.w+v[3],
                       a1.x+v[4], a1.y+v[5], a1.z+v[6], a1.w+v[7]};
        bf16x8 ob;
#pragma unroll
        for (int n = 0; n < 8; n++) ob[n] = (short)f2bf(av[n]);
        *(bf16x8*)&ldsB[wv][rbase + j][cbase] = ob;
    }

    // ---- stage 2: emb = l2norm(acc @ Wemb + bemb) ----
    ZACC();
    MM128(*(const bf16x8*)&ldsB[wv][lr][ks * 32 + lk8], Wembt);
    {
        float bv[8]; LDBIAS(bv, bemb);
#pragma unroll
        for (int j = 0; j < 4; j++) {
            int row = row0 + rbase + j;
            float v[8];
#pragma unroll
            for (int n = 0; n < 8; n++) v[n] = acc[n][j] + bv[n];
            L2NORM(v);
            if (row < M) {
                size_t base = ((size_t)row << 7) + cbase;
                *(float4*)(embO + base)     = make_float4(v[0], v[1], v[2], v[3]);
                *(float4*)(embO + base + 4) = make_float4(v[4], v[5], v[6], v[7]);
            }
        }
    }

    // ---- stage 3: lft0 = tanh(n1 @ Wl0 + bl0) + n1 ----
    ZACC();
    MM128(*(const bf16x8*)&ldsA[wv][lr][ks * 32 + lk8], Wl0t);
    {
        float bv[8]; LDBIAS(bv, bl);
#pragma unroll
        for (int j = 0; j < 4; j++) {
            bf16x8 rv = *(const bf16x8*)&ldsA[wv][rbase + j][cbase];
            bf16x8 ob;
#pragma unroll
            for (int n = 0; n < 8; n++)
                ob[n] = (short)f2bf(tanhf(acc[n][j] + bv[n]) + bf2f((unsigned short)rv[n]));
            *(bf16x8*)&ldsB[wv][rbase + j][cbase] = ob;
        }
    }

    // ---- stage 4: lft = tanh(lft0 @ Wl1 + bl1) ----
    ZACC();
    MM128(*(const bf16x8*)&ldsB[wv][lr][ks * 32 + lk8], Wl1t);
    {
        float bv[8]; LDBIAS(bv, bl + 128);
#pragma unroll
        for (int j = 0; j < 4; j++) {
            int row = row0 + rbase + j;
            if (row < M) {
                size_t base = ((size_t)row << 7) + cbase;
                *(float4*)(lftO + base)     = make_float4(tanhf(acc[0][j]+bv[0]), tanhf(acc[1][j]+bv[1]),
                                                          tanhf(acc[2][j]+bv[2]), tanhf(acc[3][j]+bv[3]));
                *(float4*)(lftO + base + 4) = make_float4(tanhf(acc[4][j]+bv[4]), tanhf(acc[5][j]+bv[5]),
                                                          tanhf(acc[6][j]+bv[6]), tanhf(acc[7][j]+bv[7]));
            }
        }
    }

    // ---- stage 5: rgt0 = tanh(n1 @ Wr0 + br0) + n1 ----
    ZACC();
    MM128(*(const bf16x8*)&ldsA[wv][lr][ks * 32 + lk8], Wr0t);
    {
        float bv[8]; LDBIAS(bv, br);
#pragma unroll
        for (int j = 0; j < 4; j++) {
            bf16x8 rv = *(const bf16x8*)&ldsA[wv][rbase + j][cbase];
            bf16x8 ob;
#pragma unroll
            for (int n = 0; n < 8; n++)
                ob[n] = (short)f2bf(tanhf(acc[n][j] + bv[n]) + bf2f((unsigned short)rv[n]));
            *(bf16x8*)&ldsB[wv][rbase + j][cbase] = ob;
        }
    }

    // ---- stage 6: rgt = tanh(rgt0 @ Wr1 + br1) ----
    ZACC();
    MM128(*(const bf16x8*)&ldsB[wv][lr][ks * 32 + lk8], Wr1t);
    {
        float bv[8]; LDBIAS(bv, br + 128);
#pragma unroll
        for (int j = 0; j < 4; j++) {
            int row = row0 + rbase + j;
            if (row < M) {
                size_t base = ((size_t)row << 7) + cbase;
                *(float4*)(rgtO + base)     = make_float4(tanhf(acc[0][j]+bv[0]), tanhf(acc[1][j]+bv[1]),
                                                          tanhf(acc[2][j]+bv[2]), tanhf(acc[3][j]+bv[3]));
                *(float4*)(rgtO + base + 4) = make_float4(tanhf(acc[4][j]+bv[4]), tanhf(acc[5][j]+bv[5]),
                                                          tanhf(acc[6][j]+bv[6]), tanhf(acc[7][j]+bv[7]));
            }
        }
    }
#undef ZACC
#undef MM128
#undef LDBIAS
#undef L2NORM
}

// ============ bucketed CSR build ============
#define RCHUNK 16384

__global__ __launch_bounds__(256)
void bhist_k(const int* __restrict__ rows, int* __restrict__ bcnt, int E, int NB)
{
    __shared__ int lc[1024];
    for (int b = threadIdx.x; b < NB; b += 256) lc[b] = 0;
    __syncthreads();
    int start = blockIdx.x * RCHUNK;
    int end = min(start + RCHUNK, E);
    for (int i = start + threadIdx.x; i < end; i += 256)
        atomicAdd(&lc[rows[i] >> 7], 1);
    __syncthreads();
    for (int b = threadIdx.x; b < NB; b += 256)
        if (lc[b]) atomicAdd(&bcnt[b], lc[b]);
}

__global__ __launch_bounds__(256)
void bucket_scan(const int* __restrict__ bcnt, int* __restrict__ bbase,
                 int* __restrict__ bcur, int NB)
{
    __shared__ int sdata[256];
    const int tid = threadIdx.x;
    int loc[4]; int s = 0;
#pragma unroll
    for (int j = 0; j < 4; j++) {
        int i = tid * 4 + j;
        int v = (i < NB) ? bcnt[i] : 0;
        loc[j] = s; s += v;
    }
    sdata[tid] = s;
    __syncthreads();
    int x = s;
    for (int off = 1; off < 256; off <<= 1) {
        int t = 0;
        if (tid >= off) t = sdata[tid - off];
        __syncthreads();
        x += t;
        sdata[tid] = x;
        __syncthreads();
    }
    int excl = x - s;
#pragma unroll
    for (int j = 0; j < 4; j++) {
        int i = tid * 4 + j;
        if (i < NB) { bbase[i] = excl + loc[j]; bcur[i] = excl + loc[j]; }
    }
    if (tid == 255) bbase[NB] = x;
}

__global__ __launch_bounds__(256)
void bucket_scatter(const int* __restrict__ rows, const int* __restrict__ cols,
                    const float* __restrict__ vals, int* __restrict__ bcur,
                    int2* __restrict__ tmp, int E, int NB)
{
    __shared__ int lcnt[1024];
    __shared__ int lbase[1024];
    for (int b = threadIdx.x; b < NB; b += 256) lcnt[b] = 0;
    __syncthreads();
    int start = blockIdx.x * RCHUNK;
    int end = min(start + RCHUNK, E);
    for (int i = start + threadIdx.x; i < end; i += 256)
        atomicAdd(&lcnt[rows[i] >> 7], 1);
    __syncthreads();
    for (int b = threadIdx.x; b < NB; b += 256) {
        int c = lcnt[b];
        lbase[b] = c ? atomicAdd(&bcur[b], c) : 0;
        lcnt[b] = 0;
    }
    __syncthreads();
    for (int i = start + threadIdx.x; i < end; i += 256) {
        int r = rows[i];
        int b = r >> 7;
        int off = atomicAdd(&lcnt[b], 1);
        tmp[lbase[b] + off] = make_int2(cols[i] | ((r & 127) << 17), __float_as_int(vals[i]));
    }
}

__global__ __launch_bounds__(256)
void csr_place(const int2* __restrict__ tmp, const int* __restrict__ bbase,
               int* __restrict__ rowptr, int2* __restrict__ packed, int M, int NB)
{
    __shared__ int lcnt[128];
    __shared__ int lofs[128];
    const int tid = threadIdx.x;
    const int b = blockIdx.x;
    const int s = bbase[b], e = bbase[b + 1];
    const int rb = b << 7;
    if (tid < 128) lcnt[tid] = 0;
    __syncthreads();
    for (int i = s + tid; i < e; i += 256)
        atomicAdd(&lcnt[(((unsigned)tmp[i].x) >> 17) & 127], 1);
    __syncthreads();
    if (tid == 0) {
        int run = s;
#pragma unroll 8
        for (int r = 0; r < 128; r++) { lofs[r] = run; run += lcnt[r]; }
    }
    __syncthreads();
    if (tid < 128 && rb + tid < M) rowptr[rb + tid] = lofs[tid];
    if (b == NB - 1 && tid == 0) rowptr[M] = e;
    if (tid < 128) lcnt[tid] = 0;
    __syncthreads();
    for (int i = s + tid; i < e; i += 256) {
        int2 t = tmp[i];
        int rl = (((unsigned)t.x) >> 17) & 127;
        int pos = lofs[rl] + atomicAdd(&lcnt[rl], 1);
        packed[pos] = make_int2(t.x & 0x1FFFF, t.y);
    }
}

// ============ CSR SpMM: 16 lanes/edge x 4 edge-groups, 16B gathers ============
__global__ __launch_bounds__(256)
void spmm_csr(const int* __restrict__ rowptr, const int2* __restrict__ packed,
              const unsigned short* __restrict__ embb, unsigned short* __restrict__ hb, int N)
{
    const int wv = threadIdx.x >> 6, lane = threadIdx.x & 63;
    const int g = lane >> 4, q = lane & 15;
    const int r = blockIdx.x * 4 + wv;
    if (r >= N) return;
    const int s = rowptr[r], e = rowptr[r + 1];
    const unsigned short* __restrict__ eb = embb + q * 8;

    float a0=0.f,a1=0.f,a2=0.f,a3=0.f,a4=0.f,a5=0.f,a6=0.f,a7=0.f;
    int i = s + g;
    for (; i + 12 < e; i += 16) {
#pragma unroll
        for (int u = 0; u < 4; u++) {
            int2 p = packed[i + 4 * u];
            uint4 m = *(const uint4*)(eb + ((size_t)p.x << 7));
            float v = __int_as_float(p.y);
            a0 += v * __uint_as_float(m.x << 16);
            a1 += v * __uint_as_float(m.x & 0xffff0000u);
            a2 += v * __uint_as_float(m.y << 16);
            a3 += v * __uint_as_float(m.y & 0xffff0000u);
            a4 += v * __uint_as_float(m.z << 16);
            a5 += v * __uint_as_float(m.z & 0xffff0000u);
            a6 += v * __uint_as_float(m.w << 16);
            a7 += v * __uint_as_float(m.w & 0xffff0000u);
        }
    }
    for (; i < e; i += 4) {
        int2 p = packed[i];
        uint4 m = *(const uint4*)(eb + ((size_t)p.x << 7));
        float v = __int_as_float(p.y);
        a0 += v * __uint_as_float(m.x << 16);
        a1 += v * __uint_as_float(m.x & 0xffff0000u);
        a2 += v * __uint_as_float(m.y << 16);
        a3 += v * __uint_as_float(m.y & 0xffff0000u);
        a4 += v * __uint_as_float(m.z << 16);
        a5 += v * __uint_as_float(m.z & 0xffff0000u);
        a6 += v * __uint_as_float(m.w << 16);
        a7 += v * __uint_as_float(m.w & 0xffff0000u);
    }
#pragma unroll
    for (int msk = 16; msk <= 32; msk <<= 1) {
        a0 += __shfl_xor(a0, msk); a1 += __shfl_xor(a1, msk);
        a2 += __shfl_xor(a2, msk); a3 += __shfl_xor(a3, msk);
        a4 += __shfl_xor(a4, msk); a5 += __shfl_xor(a5, msk);
        a6 += __shfl_xor(a6, msk); a7 += __shfl_xor(a7, msk);
    }
    if (g == 0) {
        unsigned o0 = (unsigned)f2bf(a0) | ((unsigned)f2bf(a1) << 16);
        unsigned o1 = (unsigned)f2bf(a2) | ((unsigned)f2bf(a3) << 16);
        unsigned o2 = (unsigned)f2bf(a4) | ((unsigned)f2bf(a5) << 16);
        unsigned o3 = (unsigned)f2bf(a6) | ((unsigned)f2bf(a7) << 16);
        *(uint4*)(hb + ((size_t)r << 7) + q * 8) = make_uint4(o0, o1, o2, o3);
    }
}

// ============ launch ============
extern "C" void kernel_launch(void* const* d_in, const int* in_sizes, int n_in,
                              void* d_out, int out_size, void* d_ws, size_t ws_size,
                              hipStream_t stream)
{
    const float* feat  = (const float*)d_in[0];
    const int*   srows = (const int*)  d_in[1];
    const int*   scols = (const int*)  d_in[2];
    const float* svals = (const float*)d_in[3];
    const float* Wf0   = (const float*)d_in[4];
    const float* bf0   = (const float*)d_in[5];
    const float* Wf1   = (const float*)d_in[6];
    const float* bf1   = (const float*)d_in[7];
    const float* Wg    = (const float*)d_in[8];
    const float* Wemb  = (const float*)d_in[9];
    const float* bemb  = (const float*)d_in[10];
    const float* Wl    = (const float*)d_in[11];
    const float* bl    = (const float*)d_in[12];
    const float* Wr    = (const float*)d_in[13];
    const float* br    = (const float*)d_in[14];

    const int M = in_sizes[0] / 512;   // 100000 nodes
    const int E = in_sizes[1];         // 3200000 edges
    const int NB = (M + 127) >> 7;     // 782 buckets

    float* out = (float*)d_out;
    float* R0 = out;
    float* R1 = out + (size_t)M * 128;
    float* R2 = out + (size_t)M * 256;

    // ---- ws layout ----
    float* ws = (float*)d_ws;
    float* accf = ws;                                      // [M,128] f32; tmp aliases (dead before s4)
    int2*  tmp  = (int2*)ws;
    int*   ip = (int*)(ws + (size_t)M * 128);
    int*   rowptr  = ip;                                   // M+1
    int2*  packed  = (int2*)(ip + (((size_t)M + 4) & ~(size_t)3));  // E
    int*   bcnt    = (int*)(packed + E);                   // 1024
    int*   bbase   = bcnt + 1024;                          // 1032
    int*   bcur    = bbase + 1032;                         // 1024
    unsigned short* h_ws = (unsigned short*)(bcur + 1024); // [M,128] bf16 spmm accumulator
    unsigned short* Wt0  = h_ws + (size_t)M * 128;         // [512x256] frag-major D
    unsigned short* Wt1  = Wt0 + 256 * 512;                // [256x128] frag-major D
    unsigned short* Wt7  = Wt1 + 128 * 256;                // 7 x [128x128] frag-major E

    // ---- d_out scratch timeline ----
    unsigned short* R0a = (unsigned short*)R0;
    unsigned short* R1a = (unsigned short*)R1;
    unsigned short* feat_bf = (unsigned short*)R0;  // [M,512], dead after head
    unsigned short* x_bf    = (unsigned short*)R2;  // head out; spmm3 src; s4 aux (R2 scratch, dead before tail)
    unsigned short* n0_bf   = R1a;                  // s4 -> spmm5

    dim3 blk(256);
    const int gm64 = (M + 63) / 64;
    const int nch  = (E + RCHUNK - 1) / RCHUNK;

    // weight converts
    wconvD<<<(512*256 + 255)/256, blk, 0, stream>>>(Wf0, Wt0, 512, 256);
    wconvD<<<(256*128 + 255)/256, blk, 0, stream>>>(Wf1, Wt1, 256, 128);
    wconv7<<<(7*16384 + 255)/256, blk, 0, stream>>>(Wg, Wemb, Wl, Wr, Wt7);

    // feat -> bf16 (into R0+R1 region)
    f32_to_bf16<<<(int)(((long)M * 64 + 255) / 256), blk, 0, stream>>>(feat, feat_bf, (long)M * 64);

    // ---- CSR build ----
    hipMemsetAsync(bcnt, 0, (size_t)NB * 4, stream);
    bhist_k<<<nch, blk, 0, stream>>>(srows, bcnt, E, NB);
    bucket_scan<<<1, blk, 0, stream>>>(bcnt, bbase, bcur, NB);
    bucket_scatter<<<nch, blk, 0, stream>>>(srows, scols, svals, bcur, tmp, E, NB);
    csr_place<<<NB, blk, 0, stream>>>(tmp, bbase, rowptr, packed, M, NB);

    // ---- network ----
    // head: x = tanh(tanh(feat@Wf0+bf0)@Wf1+bf1)  [fused s1+s2; x1 never leaves LDS]
    mfma_head<<<gm64, dim3(512), 0, stream>>>(feat_bf, Wt0, bf0, Wt1, bf1, x_bf, M);
    // spmm3: h = S @ x
    spmm_csr<<<(M + 3) / 4, blk, 0, stream>>>(rowptr, packed, x_bf, h_ws, M);
    // s4: n0 = l2norm(tanh(h @ Wg0)) -> n0_bf; accf = x + n0
    mfma_ep<true,true,true,false,true,true,false,true,false><<<gm64,blk,0,stream>>>(
        h_ws, Wt7 /*Wg0 frag-major*/, nullptr, nullptr, x_bf, accf, nullptr, n0_bf, M);
    // spmm5: h = S @ n0
    spmm_csr<<<(M + 3) / 4, blk, 0, stream>>>(rowptr, packed, n0_bf, h_ws, M);
    // tail: n1 -> acc -> emb(R0) / lft(R1) / rgt(R2)
    tail_fused<<<gm64, blk, 0, stream>>>(h_ws, accf, Wt7, bemb, bl, br, R0, R1, R2, M);
}

// Round 16
// 685.520 us; speedup vs baseline: 1.0643x; 1.0643x over previous
//
#include <hip/hip_runtime.h>
#include <math.h>

typedef short bf16x8 __attribute__((ext_vector_type(8)));
typedef float f32x4  __attribute__((ext_vector_type(4)));

__device__ __forceinline__ unsigned short f2bf(float x) {
    unsigned u = __float_as_uint(x);
    unsigned r = u + 0x7FFFu + ((u >> 16) & 1u);   // RNE
    return (unsigned short)(r >> 16);
}
__device__ __forceinline__ float bf2f(unsigned short b) {
    return __uint_as_float(((unsigned)b) << 16);
}
// tanh(x) = 1 - 2/(e^{2x}+1); v_exp_f32-based, ~5 inst, exact at +-inf.
__device__ __forceinline__ float fast_tanh(float x) {
    float e = __expf(2.0f * x);
    return 1.0f - 2.0f / (e + 1.0f);
}

// ============ weight converts -> FRAGMENT-MAJOR layouts ============
// Layout D: chunk (kblk=k/32, cblk=c/64, n=c&3) holds 64 lanes x 8 elems;
//   lane = (c>>2)&15 | ((k>>3)&3)<<4 ; elem = k&7.
__global__ __launch_bounds__(256)
void wconvD(const float* __restrict__ W, unsigned short* __restrict__ Wt, int K, int N)
{
    int id = blockIdx.x * 256 + threadIdx.x;
    if (id >= K * N) return;
    int c = id / K, k = id - c * K;
    int kblk = k >> 5, ksub = (k >> 3) & 3, kel = k & 7;
    int cblk = c >> 6, n = c & 3, lr = (c >> 2) & 15;
    int lane = lr + (ksub << 4);
    size_t dst = ((((size_t)kblk * (N >> 6) + cblk) * 4 + n) << 9) + (lane << 3) + kel;
    Wt[dst] = f2bf(W[(size_t)k * N + c]);
}

// Layout E (128-wide): chunk (ks=k/32, n=c&7); lane = (c>>3)&15 | ((k>>3)&3)<<4.
__global__ __launch_bounds__(256)
void wconv7(const float* __restrict__ Wg, const float* __restrict__ Wemb,
            const float* __restrict__ Wl, const float* __restrict__ Wr,
            unsigned short* __restrict__ dst)
{
    int id = blockIdx.x * 256 + threadIdx.x;    // < 7*16384
    if (id >= 7 * 16384) return;
    int m = id >> 14, r = id & 16383;
    int c = r >> 7, k = r & 127;
    const float* src = (m < 2) ? (Wg + m * 16384)
                     : (m == 2) ? Wemb
                     : (m < 5) ? (Wl + (m - 3) * 16384)
                               : (Wr + (m - 5) * 16384);
    int n = c & 7, lr = (c >> 3) & 15;
    int ks = k >> 5, ksub = (k >> 3) & 3, kel = k & 7;
    int lane = lr + (ksub << 4);
    dst[(size_t)m * 16384 + (((ks << 3) + n) << 9) + (lane << 3) + kel] = f2bf(src[(size_t)k * 128 + c]);
}

// ============ bulk f32 -> bf16 ============
__global__ __launch_bounds__(256)
void f32_to_bf16(const float* __restrict__ in, unsigned short* __restrict__ outb, long n8)
{
    long id = (long)blockIdx.x * 256 + threadIdx.x;
    if (id >= n8) return;
    const float4* p = (const float4*)(in + id * 8);
    float4 a = p[0], b = p[1];
    *(ushort4*)(outb + id * 8)     = make_ushort4(f2bf(a.x), f2bf(a.y), f2bf(a.z), f2bf(a.w));
    *(ushort4*)(outb + id * 8 + 4) = make_ushort4(f2bf(b.x), f2bf(b.y), f2bf(b.z), f2bf(b.w));
}

// ============ fused head: x = tanh( tanh(feat@Wf0+bf0) @ Wf1 + bf1 ) ============
__global__ __launch_bounds__(512)
void mfma_head(const unsigned short* __restrict__ Ab, const unsigned short* __restrict__ Wt0,
               const float* __restrict__ bf0, const unsigned short* __restrict__ Wt1,
               const float* __restrict__ bf1, unsigned short* __restrict__ x_bf, int M)
{
    __shared__ __align__(16) unsigned short x1s[4][16][264];   // 33.8 KB

    const int tid  = threadIdx.x;
    const int wv   = tid >> 6, lane = tid & 63;
    const int rg   = wv >> 1, ch = wv & 1;
    const int lr   = lane & 15;
    const int lk8  = (lane >> 4) * 8;
    const int rbase = (lane >> 4) * 4;
    const int row0 = blockIdx.x * 64 + rg * 16;

    // ---- stage 1: 16 rows x 128 cols (panels ch*2, ch*2+1) ----
    const unsigned short* arow;
    { int r = row0 + lr; r = r < M ? r : (M - 1); arow = Ab + (size_t)r * 512 + lk8; }
    const unsigned short* bb0 = Wt0 + ((((size_t)ch * 2) * 4) << 9) + (lane << 3);

    f32x4 acc1[8];
#pragma unroll
    for (int s = 0; s < 8; s++)
#pragma unroll
        for (int q = 0; q < 4; q++) acc1[s][q] = 0.f;

#pragma unroll 4
    for (int kb = 0; kb < 16; kb++) {
        bf16x8 af = *(const bf16x8*)(arow + kb * 32);
        bf16x8 bn[8];
        const unsigned short* bk = bb0 + (((size_t)kb * 16) << 9);
#pragma unroll
        for (int s = 0; s < 8; s++) bn[s] = *(const bf16x8*)(bk + ((size_t)s << 9));
#pragma unroll
        for (int s = 0; s < 8; s++)
            acc1[s] = __builtin_amdgcn_mfma_f32_16x16x32_bf16(af, bn[s], acc1[s], 0, 0, 0);
    }

    // epilogue 1 -> LDS (bf16)
#pragma unroll
    for (int cb = 0; cb < 2; cb++) {
        int colp = (ch * 2 + cb) * 64 + lr * 4;
        float4 b4 = *(const float4*)(bf0 + colp);
        float bv[4] = {b4.x, b4.y, b4.z, b4.w};
#pragma unroll
        for (int j = 0; j < 4; j++) {
            ushort4 o;
            o.x = f2bf(fast_tanh(acc1[cb * 4 + 0][j] + bv[0]));
            o.y = f2bf(fast_tanh(acc1[cb * 4 + 1][j] + bv[1]));
            o.z = f2bf(fast_tanh(acc1[cb * 4 + 2][j] + bv[2]));
            o.w = f2bf(fast_tanh(acc1[cb * 4 + 3][j] + bv[3]));
            *(ushort4*)&x1s[rg][rbase + j][colp] = o;
        }
    }
    __syncthreads();

    // ---- stage 2: 16 rows x 64 cols (panel ch) from LDS A-frags ----
    const unsigned short* bb1 = Wt1 + ((((size_t)ch) * 4) << 9) + (lane << 3);

    f32x4 acc2[4];
#pragma unroll
    for (int n = 0; n < 4; n++)
#pragma unroll
        for (int q = 0; q < 4; q++) acc2[n][q] = 0.f;

#pragma unroll 4
    for (int ks = 0; ks < 8; ks++) {
        bf16x8 af = *(const bf16x8*)&x1s[rg][lr][ks * 32 + lk8];
        bf16x8 bn[4];
        const unsigned short* bk = bb1 + (((size_t)ks * 8) << 9);
#pragma unroll
        for (int n = 0; n < 4; n++) bn[n] = *(const bf16x8*)(bk + ((size_t)n << 9));
#pragma unroll
        for (int n = 0; n < 4; n++)
            acc2[n] = __builtin_amdgcn_mfma_f32_16x16x32_bf16(af, bn[n], acc2[n], 0, 0, 0);
    }

    const int cbase = ch * 64 + lr * 4;
    float4 b4 = *(const float4*)(bf1 + cbase);
    float bv[4] = {b4.x, b4.y, b4.z, b4.w};
#pragma unroll
    for (int j = 0; j < 4; j++) {
        int row = row0 + rbase + j;
        if (row < M) {
            ushort4 o;
            o.x = f2bf(fast_tanh(acc2[0][j] + bv[0]));
            o.y = f2bf(fast_tanh(acc2[1][j] + bv[1]));
            o.z = f2bf(fast_tanh(acc2[2][j] + bv[2]));
            o.w = f2bf(fast_tanh(acc2[3][j] + bv[3]));
            *(ushort4*)(x_bf + ((size_t)row << 7) + cbase) = o;
        }
    }
}

// ============ MFMA K=128 single-tile, fragment-major B, fused epilogue (s4) ============
template<bool ABF16, bool TANH, bool L2, bool RESID, bool AUX, bool AUXBF,
         bool F32OUT, bool BF16OUT, bool BIAS>
__global__ __launch_bounds__(256, 4)
void mfma_ep(const void* __restrict__ A_, const unsigned short* __restrict__ Wt,
             const float* __restrict__ bias, const unsigned short* __restrict__ resid_bf,
             const void* __restrict__ aux_in, float* __restrict__ aux_out,
             float* __restrict__ out, unsigned short* __restrict__ out_bf, int M)
{
    const int tid  = threadIdx.x;
    const int row0 = blockIdx.x * 64;
    const int wv   = tid >> 6, lane = tid & 63;
    const int lr   = lane & 15;
    const int lk8  = (lane >> 4) * 8;
    const int wr   = wv * 16;

    const unsigned short* Abr;
    const float*          Afr;
    {
        int r = row0 + wr + lr;
        r = r < M ? r : (M - 1);
        Abr = (const unsigned short*)A_ + ((size_t)r << 7) + lk8;
        Afr = (const float*)A_          + ((size_t)r << 7) + lk8;
    }
    const unsigned short* wb = Wt + (lane << 3);

    f32x4 acc[8];
#pragma unroll
    for (int n = 0; n < 8; n++)
#pragma unroll
        for (int j = 0; j < 4; j++) acc[n][j] = 0.f;

#pragma unroll 2
    for (int ks = 0; ks < 4; ks++) {
        bf16x8 af, bn[8];
        if (ABF16) af = *(const bf16x8*)(Abr + ks * 32);
        else {
            float4 a = *(const float4*)(Afr + ks * 32);
            float4 b = *(const float4*)(Afr + ks * 32 + 4);
            af[0]=(short)f2bf(a.x); af[1]=(short)f2bf(a.y); af[2]=(short)f2bf(a.z); af[3]=(short)f2bf(a.w);
            af[4]=(short)f2bf(b.x); af[5]=(short)f2bf(b.y); af[6]=(short)f2bf(b.z); af[7]=(short)f2bf(b.w);
        }
#pragma unroll
        for (int n = 0; n < 8; n++)
            bn[n] = *(const bf16x8*)(wb + ((((ks << 3) + n)) << 9));
#pragma unroll
        for (int n = 0; n < 8; n++)
            acc[n] = __builtin_amdgcn_mfma_f32_16x16x32_bf16(af, bn[n], acc[n], 0, 0, 0);
    }

    const int cbase = lr * 8;
    float bv[8];
    if (BIAS) {
        float4 b0 = *(const float4*)(bias + cbase);
        float4 b1 = *(const float4*)(bias + cbase + 4);
        bv[0]=b0.x; bv[1]=b0.y; bv[2]=b0.z; bv[3]=b0.w;
        bv[4]=b1.x; bv[5]=b1.y; bv[6]=b1.z; bv[7]=b1.w;
    } else {
#pragma unroll
        for (int n = 0; n < 8; n++) bv[n] = 0.f;
    }
    const int rbase = (lane >> 4) * 4;

#pragma unroll
    for (int j = 0; j < 4; j++) {
        int row = row0 + wr + rbase + j;
        bool ok = row < M;
        size_t base = ((size_t)row << 7) + cbase;
        float v[8];
#pragma unroll
        for (int n = 0; n < 8; n++) {
            v[n] = acc[n][j] + bv[n];
            if (TANH) v[n] = fast_tanh(v[n]);
        }
        if (RESID) {
            if (ok) {
                bf16x8 rv = *(const bf16x8*)(resid_bf + base);
#pragma unroll
                for (int n = 0; n < 8; n++) v[n] += bf2f((unsigned short)rv[n]);
            }
        }
        if (L2) {
            float s = 0.f;
#pragma unroll
            for (int n = 0; n < 8; n++) s += v[n] * v[n];
#pragma unroll
            for (int msk = 8; msk >= 1; msk >>= 1) s += __shfl_xor(s, msk);
            float sc = 1.f / fmaxf(sqrtf(s), 1e-12f);
#pragma unroll
            for (int n = 0; n < 8; n++) v[n] *= sc;
        }
        if (ok) {
            if (F32OUT) {
                *(float4*)(out + base)     = make_float4(v[0], v[1], v[2], v[3]);
                *(float4*)(out + base + 4) = make_float4(v[4], v[5], v[6], v[7]);
            }
            if (BF16OUT) {
                bf16x8 o;
#pragma unroll
                for (int n = 0; n < 8; n++) o[n] = (short)f2bf(v[n]);
                *(bf16x8*)(out_bf + base) = o;
            }
            if (AUX) {
                float ai[8];
                if (AUXBF) {
                    bf16x8 av = *(const bf16x8*)((const unsigned short*)aux_in + base);
#pragma unroll
                    for (int n = 0; n < 8; n++) ai[n] = bf2f((unsigned short)av[n]);
                } else {
                    float4 a0 = *(const float4*)((const float*)aux_in + base);
                    float4 a1 = *(const float4*)((const float*)aux_in + base + 4);
                    ai[0]=a0.x; ai[1]=a0.y; ai[2]=a0.z; ai[3]=a0.w;
                    ai[4]=a1.x; ai[5]=a1.y; ai[6]=a1.z; ai[7]=a1.w;
                }
                *(float4*)(aux_out + base)     = make_float4(ai[0]+v[0], ai[1]+v[1], ai[2]+v[2], ai[3]+v[3]);
                *(float4*)(aux_out + base + 4) = make_float4(ai[4]+v[4], ai[5]+v[5], ai[6]+v[6], ai[7]+v[7]);
            }
        }
    }
}

// ============ fused tail (fragment-major weights) ============
__global__ __launch_bounds__(256, 4)
void tail_fused(const unsigned short* __restrict__ h_bf, const float* __restrict__ accf,
                const unsigned short* __restrict__ Wt7,
                const float* __restrict__ bemb, const float* __restrict__ bl,
                const float* __restrict__ br,
                float* __restrict__ embO, float* __restrict__ lftO,
                float* __restrict__ rgtO, int M)
{
    __shared__ __align__(16) unsigned short ldsA[4][16][136];  // n1
    __shared__ __align__(16) unsigned short ldsB[4][16][136];  // acc / lft0 / rgt0

    const int tid = threadIdx.x;
    const int wv = tid >> 6, lane = tid & 63;
    const int lr = lane & 15;
    const int lk8 = (lane >> 4) * 8;
    const int rbase = (lane >> 4) * 4;
    const int row0 = blockIdx.x * 64 + wv * 16;
    const int cbase = lr * 8;

    const unsigned short* Wg1t  = Wt7 + 1 * 16384 + (lane << 3);
    const unsigned short* Wembt = Wt7 + 2 * 16384 + (lane << 3);
    const unsigned short* Wl0t  = Wt7 + 3 * 16384 + (lane << 3);
    const unsigned short* Wl1t  = Wt7 + 4 * 16384 + (lane << 3);
    const unsigned short* Wr0t  = Wt7 + 5 * 16384 + (lane << 3);
    const unsigned short* Wr1t  = Wt7 + 6 * 16384 + (lane << 3);

    f32x4 acc[8];

#define ZACC() { _Pragma("unroll") for (int n = 0; n < 8; n++) \
                 _Pragma("unroll") for (int q = 0; q < 4; q++) acc[n][q] = 0.f; }
#define MM128(AFRAG, WPTR)                                                            \
    _Pragma("unroll")                                                                 \
    for (int ks = 0; ks < 4; ks++) {                                                  \
        bf16x8 af = (AFRAG);                                                          \
        bf16x8 bn[8];                                                                 \
        _Pragma("unroll")                                                             \
        for (int n = 0; n < 8; n++)                                                   \
            bn[n] = *(const bf16x8*)((WPTR) + ((((ks << 3) + n)) << 9));              \
        _Pragma("unroll")                                                             \
        for (int n = 0; n < 8; n++)                                                   \
            acc[n] = __builtin_amdgcn_mfma_f32_16x16x32_bf16(af, bn[n], acc[n], 0, 0, 0); \
    }
#define LDBIAS(BV, P) { float4 b0_ = *(const float4*)((P) + cbase);                   \
                        float4 b1_ = *(const float4*)((P) + cbase + 4);               \
                        BV[0]=b0_.x; BV[1]=b0_.y; BV[2]=b0_.z; BV[3]=b0_.w;           \
                        BV[4]=b1_.x; BV[5]=b1_.y; BV[6]=b1_.z; BV[7]=b1_.w; }
#define L2NORM(V) { float s_ = 0.f;                                                   \
                    _Pragma("unroll") for (int n = 0; n < 8; n++) s_ += V[n]*V[n];    \
                    _Pragma("unroll") for (int mk = 8; mk >= 1; mk >>= 1) s_ += __shfl_xor(s_, mk); \
                    float sc_ = 1.f / fmaxf(sqrtf(s_), 1e-12f);                       \
                    _Pragma("unroll") for (int n = 0; n < 8; n++) V[n] *= sc_; }

    // ---- stage 1: n1 = l2norm(tanh(h @ Wg1)); acc = accf + n1 ----
    const unsigned short* hrow;
    {
        int r = row0 + lr;
        r = r < M ? r : (M - 1);
        hrow = h_bf + ((size_t)r << 7) + lk8;
    }
    ZACC();
    MM128(*(const bf16x8*)(hrow + ks * 32), Wg1t);
#pragma unroll
    for (int j = 0; j < 4; j++) {
        int row = row0 + rbase + j;
        int rc = row < M ? row : (M - 1);
        float v[8];
#pragma unroll
        for (int n = 0; n < 8; n++) v[n] = fast_tanh(acc[n][j]);
        L2NORM(v);
        bf16x8 o;
#pragma unroll
        for (int n = 0; n < 8; n++) o[n] = (short)f2bf(v[n]);
        *(bf16x8*)&ldsA[wv][rbase + j][cbase] = o;
        float4 a0 = *(const float4*)(accf + ((size_t)rc << 7) + cbase);
        float4 a1 = *(const float4*)(accf + ((size_t)rc << 7) + cbase + 4);
        float av[8] = {a0.x+v[0], a0.y+v[1], a0.z+v[2], a0.w+v[3],
                       a1.x+v[4], a1.y+v[5], a1.z+v[6], a1.w+v[7]};
        bf16x8 ob;
#pragma unroll
        for (int n = 0; n < 8; n++) ob[n] = (short)f2bf(av[n]);
        *(bf16x8*)&ldsB[wv][rbase + j][cbase] = ob;
    }

    // ---- stage 2: emb = l2norm(acc @ Wemb + bemb) ----
    ZACC();
    MM128(*(const bf16x8*)&ldsB[wv][lr][ks * 32 + lk8], Wembt);
    {
        float bv[8]; LDBIAS(bv, bemb);
#pragma unroll
        for (int j = 0; j < 4; j++) {
            int row = row0 + rbase + j;
            float v[8];
#pragma unroll
            for (int n = 0; n < 8; n++) v[n] = acc[n][j] + bv[n];
            L2NORM(v);
            if (row < M) {
                size_t base = ((size_t)row << 7) + cbase;
                *(float4*)(embO + base)     = make_float4(v[0], v[1], v[2], v[3]);
                *(float4*)(embO + base + 4) = make_float4(v[4], v[5], v[6], v[7]);
            }
        }
    }

    // ---- stage 3: lft0 = tanh(n1 @ Wl0 + bl0) + n1 ----
    ZACC();
    MM128(*(const bf16x8*)&ldsA[wv][lr][ks * 32 + lk8], Wl0t);
    {
        float bv[8]; LDBIAS(bv, bl);
#pragma unroll
        for (int j = 0; j < 4; j++) {
            bf16x8 rv = *(const bf16x8*)&ldsA[wv][rbase + j][cbase];
            bf16x8 ob;
#pragma unroll
            for (int n = 0; n < 8; n++)
                ob[n] = (short)f2bf(fast_tanh(acc[n][j] + bv[n]) + bf2f((unsigned short)rv[n]));
            *(bf16x8*)&ldsB[wv][rbase + j][cbase] = ob;
        }
    }

    // ---- stage 4: lft = tanh(lft0 @ Wl1 + bl1) ----
    ZACC();
    MM128(*(const bf16x8*)&ldsB[wv][lr][ks * 32 + lk8], Wl1t);
    {
        float bv[8]; LDBIAS(bv, bl + 128);
#pragma unroll
        for (int j = 0; j < 4; j++) {
            int row = row0 + rbase + j;
            if (row < M) {
                size_t base = ((size_t)row << 7) + cbase;
                *(float4*)(lftO + base)     = make_float4(fast_tanh(acc[0][j]+bv[0]), fast_tanh(acc[1][j]+bv[1]),
                                                          fast_tanh(acc[2][j]+bv[2]), fast_tanh(acc[3][j]+bv[3]));
                *(float4*)(lftO + base + 4) = make_float4(fast_tanh(acc[4][j]+bv[4]), fast_tanh(acc[5][j]+bv[5]),
                                                          fast_tanh(acc[6][j]+bv[6]), fast_tanh(acc[7][j]+bv[7]));
            }
        }
    }

    // ---- stage 5: rgt0 = tanh(n1 @ Wr0 + br0) + n1 ----
    ZACC();
    MM128(*(const bf16x8*)&ldsA[wv][lr][ks * 32 + lk8], Wr0t);
    {
        float bv[8]; LDBIAS(bv, br);
#pragma unroll
        for (int j = 0; j < 4; j++) {
            bf16x8 rv = *(const bf16x8*)&ldsA[wv][rbase + j][cbase];
            bf16x8 ob;
#pragma unroll
            for (int n = 0; n < 8; n++)
                ob[n] = (short)f2bf(fast_tanh(acc[n][j] + bv[n]) + bf2f((unsigned short)rv[n]));
            *(bf16x8*)&ldsB[wv][rbase + j][cbase] = ob;
        }
    }

    // ---- stage 6: rgt = tanh(rgt0 @ Wr1 + br1) ----
    ZACC();
    MM128(*(const bf16x8*)&ldsB[wv][lr][ks * 32 + lk8], Wr1t);
    {
        float bv[8]; LDBIAS(bv, br + 128);
#pragma unroll
        for (int j = 0; j < 4; j++) {
            int row = row0 + rbase + j;
            if (row < M) {
                size_t base = ((size_t)row << 7) + cbase;
                *(float4*)(rgtO + base)     = make_float4(fast_tanh(acc[0][j]+bv[0]), fast_tanh(acc[1][j]+bv[1]),
                                                          fast_tanh(acc[2][j]+bv[2]), fast_tanh(acc[3][j]+bv[3]));
                *(float4*)(rgtO + base + 4) = make_float4(fast_tanh(acc[4][j]+bv[4]), fast_tanh(acc[5][j]+bv[5]),
                                                          fast_tanh(acc[6][j]+bv[6]), fast_tanh(acc[7][j]+bv[7]));
            }
        }
    }
#undef ZACC
#undef MM128
#undef LDBIAS
#undef L2NORM
}

// ============ bucketed CSR build ============
#define RCHUNK 16384

__global__ __launch_bounds__(256)
void bhist_k(const int* __restrict__ rows, int* __restrict__ bcnt, int E, int NB)
{
    __shared__ int lc[1024];
    for (int b = threadIdx.x; b < NB; b += 256) lc[b] = 0;
    __syncthreads();
    int start = blockIdx.x * RCHUNK;
    int end = min(start + RCHUNK, E);
    for (int i = start + threadIdx.x; i < end; i += 256)
        atomicAdd(&lc[rows[i] >> 7], 1);
    __syncthreads();
    for (int b = threadIdx.x; b < NB; b += 256)
        if (lc[b]) atomicAdd(&bcnt[b], lc[b]);
}

__global__ __launch_bounds__(256)
void bucket_scan(const int* __restrict__ bcnt, int* __restrict__ bbase,
                 int* __restrict__ bcur, int NB)
{
    __shared__ int sdata[256];
    const int tid = threadIdx.x;
    int loc[4]; int s = 0;
#pragma unroll
    for (int j = 0; j < 4; j++) {
        int i = tid * 4 + j;
        int v = (i < NB) ? bcnt[i] : 0;
        loc[j] = s; s += v;
    }
    sdata[tid] = s;
    __syncthreads();
    int x = s;
    for (int off = 1; off < 256; off <<= 1) {
        int t = 0;
        if (tid >= off) t = sdata[tid - off];
        __syncthreads();
        x += t;
        sdata[tid] = x;
        __syncthreads();
    }
    int excl = x - s;
#pragma unroll
    for (int j = 0; j < 4; j++) {
        int i = tid * 4 + j;
        if (i < NB) { bbase[i] = excl + loc[j]; bcur[i] = excl + loc[j]; }
    }
    if (tid == 255) bbase[NB] = x;
}

__global__ __launch_bounds__(256)
void bucket_scatter(const int* __restrict__ rows, const int* __restrict__ cols,
                    const float* __restrict__ vals, int* __restrict__ bcur,
                    int2* __restrict__ tmp, int E, int NB)
{
    __shared__ int lcnt[1024];
    __shared__ int lbase[1024];
    for (int b = threadIdx.x; b < NB; b += 256) lcnt[b] = 0;
    __syncthreads();
    int start = blockIdx.x * RCHUNK;
    int end = min(start + RCHUNK, E);
    for (int i = start + threadIdx.x; i < end; i += 256)
        atomicAdd(&lcnt[rows[i] >> 7], 1);
    __syncthreads();
    for (int b = threadIdx.x; b < NB; b += 256) {
        int c = lcnt[b];
        lbase[b] = c ? atomicAdd(&bcur[b], c) : 0;
        lcnt[b] = 0;
    }
    __syncthreads();
    for (int i = start + threadIdx.x; i < end; i += 256) {
        int r = rows[i];
        int b = r >> 7;
        int off = atomicAdd(&lcnt[b], 1);
        tmp[lbase[b] + off] = make_int2(cols[i] | ((r & 127) << 17), __float_as_int(vals[i]));
    }
}

__global__ __launch_bounds__(256)
void csr_place(const int2* __restrict__ tmp, const int* __restrict__ bbase,
               int* __restrict__ rowptr, int2* __restrict__ packed, int M, int NB)
{
    __shared__ int lcnt[128];
    __shared__ int lofs[128];
    const int tid = threadIdx.x;
    const int b = blockIdx.x;
    const int s = bbase[b], e = bbase[b + 1];
    const int rb = b << 7;
    if (tid < 128) lcnt[tid] = 0;
    __syncthreads();
    for (int i = s + tid; i < e; i += 256)
        atomicAdd(&lcnt[(((unsigned)tmp[i].x) >> 17) & 127], 1);
    __syncthreads();
    if (tid == 0) {
        int run = s;
#pragma unroll 8
        for (int r = 0; r < 128; r++) { lofs[r] = run; run += lcnt[r]; }
    }
    __syncthreads();
    if (tid < 128 && rb + tid < M) rowptr[rb + tid] = lofs[tid];
    if (b == NB - 1 && tid == 0) rowptr[M] = e;
    if (tid < 128) lcnt[tid] = 0;
    __syncthreads();
    for (int i = s + tid; i < e; i += 256) {
        int2 t = tmp[i];
        int rl = (((unsigned)t.x) >> 17) & 127;
        int pos = lofs[rl] + atomicAdd(&lcnt[rl], 1);
        packed[pos] = make_int2(t.x & 0x1FFFF, t.y);
    }
}

// ============ CSR SpMM: 16 lanes/edge x 4 edge-groups, 16B gathers ============
__global__ __launch_bounds__(256)
void spmm_csr(const int* __restrict__ rowptr, const int2* __restrict__ packed,
              const unsigned short* __restrict__ embb, unsigned short* __restrict__ hb, int N)
{
    const int wv = threadIdx.x >> 6, lane = threadIdx.x & 63;
    const int g = lane >> 4, q = lane & 15;
    const int r = blockIdx.x * 4 + wv;
    if (r >= N) return;
    const int s = rowptr[r], e = rowptr[r + 1];
    const unsigned short* __restrict__ eb = embb + q * 8;

    float a0=0.f,a1=0.f,a2=0.f,a3=0.f,a4=0.f,a5=0.f,a6=0.f,a7=0.f;
    int i = s + g;
    for (; i + 12 < e; i += 16) {
#pragma unroll
        for (int u = 0; u < 4; u++) {
            int2 p = packed[i + 4 * u];
            uint4 m = *(const uint4*)(eb + ((size_t)p.x << 7));
            float v = __int_as_float(p.y);
            a0 += v * __uint_as_float(m.x << 16);
            a1 += v * __uint_as_float(m.x & 0xffff0000u);
            a2 += v * __uint_as_float(m.y << 16);
            a3 += v * __uint_as_float(m.y & 0xffff0000u);
            a4 += v * __uint_as_float(m.z << 16);
            a5 += v * __uint_as_float(m.z & 0xffff0000u);
            a6 += v * __uint_as_float(m.w << 16);
            a7 += v * __uint_as_float(m.w & 0xffff0000u);
        }
    }
    for (; i < e; i += 4) {
        int2 p = packed[i];
        uint4 m = *(const uint4*)(eb + ((size_t)p.x << 7));
        float v = __int_as_float(p.y);
        a0 += v * __uint_as_float(m.x << 16);
        a1 += v * __uint_as_float(m.x & 0xffff0000u);
        a2 += v * __uint_as_float(m.y << 16);
        a3 += v * __uint_as_float(m.y & 0xffff0000u);
        a4 += v * __uint_as_float(m.z << 16);
        a5 += v * __uint_as_float(m.z & 0xffff0000u);
        a6 += v * __uint_as_float(m.w << 16);
        a7 += v * __uint_as_float(m.w & 0xffff0000u);
    }
#pragma unroll
    for (int msk = 16; msk <= 32; msk <<= 1) {
        a0 += __shfl_xor(a0, msk); a1 += __shfl_xor(a1, msk);
        a2 += __shfl_xor(a2, msk); a3 += __shfl_xor(a3, msk);
        a4 += __shfl_xor(a4, msk); a5 += __shfl_xor(a5, msk);
        a6 += __shfl_xor(a6, msk); a7 += __shfl_xor(a7, msk);
    }
    if (g == 0) {
        unsigned o0 = (unsigned)f2bf(a0) | ((unsigned)f2bf(a1) << 16);
        unsigned o1 = (unsigned)f2bf(a2) | ((unsigned)f2bf(a3) << 16);
        unsigned o2 = (unsigned)f2bf(a4) | ((unsigned)f2bf(a5) << 16);
        unsigned o3 = (unsigned)f2bf(a6) | ((unsigned)f2bf(a7) << 16);
        *(uint4*)(hb + ((size_t)r << 7) + q * 8) = make_uint4(o0, o1, o2, o3);
    }
}

// ============ launch ============
extern "C" void kernel_launch(void* const* d_in, const int* in_sizes, int n_in,
                              void* d_out, int out_size, void* d_ws, size_t ws_size,
                              hipStream_t stream)
{
    const float* feat  = (const float*)d_in[0];
    const int*   srows = (const int*)  d_in[1];
    const int*   scols = (const int*)  d_in[2];
    const float* svals = (const float*)d_in[3];
    const float* Wf0   = (const float*)d_in[4];
    const float* bf0   = (const float*)d_in[5];
    const float* Wf1   = (const float*)d_in[6];
    const float* bf1   = (const float*)d_in[7];
    const float* Wg    = (const float*)d_in[8];
    const float* Wemb  = (const float*)d_in[9];
    const float* bemb  = (const float*)d_in[10];
    const float* Wl    = (const float*)d_in[11];
    const float* bl    = (const float*)d_in[12];
    const float* Wr    = (const float*)d_in[13];
    const float* br    = (const float*)d_in[14];

    const int M = in_sizes[0] / 512;   // 100000 nodes
    const int E = in_sizes[1];         // 3200000 edges
    const int NB = (M + 127) >> 7;     // 782 buckets

    float* out = (float*)d_out;
    float* R0 = out;
    float* R1 = out + (size_t)M * 128;
    float* R2 = out + (size_t)M * 256;

    // ---- ws layout ----
    float* ws = (float*)d_ws;
    float* accf = ws;                                      // [M,128] f32; tmp aliases (dead before s4)
    int2*  tmp  = (int2*)ws;
    int*   ip = (int*)(ws + (size_t)M * 128);
    int*   rowptr  = ip;                                   // M+1
    int2*  packed  = (int2*)(ip + (((size_t)M + 4) & ~(size_t)3));  // E
    int*   bcnt    = (int*)(packed + E);                   // 1024
    int*   bbase   = bcnt + 1024;                          // 1032
    int*   bcur    = bbase + 1032;                         // 1024
    unsigned short* h_ws = (unsigned short*)(bcur + 1024); // [M,128] bf16 spmm accumulator
    unsigned short* Wt0  = h_ws + (size_t)M * 128;         // [512x256] frag-major D
    unsigned short* Wt1  = Wt0 + 256 * 512;                // [256x128] frag-major D
    unsigned short* Wt7  = Wt1 + 128 * 256;                // 7 x [128x128] frag-major E

    // ---- d_out scratch timeline ----
    unsigned short* R1a = (unsigned short*)R1;
    unsigned short* feat_bf = (unsigned short*)R0;  // [M,512], dead after head
    unsigned short* x_bf    = (unsigned short*)R2;  // head out; spmm3 src; s4 aux (dead before tail)
    unsigned short* n0_bf   = R1a;                  // s4 -> spmm5

    dim3 blk(256);
    const int gm64 = (M + 63) / 64;
    const int nch  = (E + RCHUNK - 1) / RCHUNK;

    // weight converts
    wconvD<<<(512*256 + 255)/256, blk, 0, stream>>>(Wf0, Wt0, 512, 256);
    wconvD<<<(256*128 + 255)/256, blk, 0, stream>>>(Wf1, Wt1, 256, 128);
    wconv7<<<(7*16384 + 255)/256, blk, 0, stream>>>(Wg, Wemb, Wl, Wr, Wt7);

    // feat -> bf16 (into R0+R1 region)
    f32_to_bf16<<<(int)(((long)M * 64 + 255) / 256), blk, 0, stream>>>(feat, feat_bf, (long)M * 64);

    // ---- CSR build ----
    hipMemsetAsync(bcnt, 0, (size_t)NB * 4, stream);
    bhist_k<<<nch, blk, 0, stream>>>(srows, bcnt, E, NB);
    bucket_scan<<<1, blk, 0, stream>>>(bcnt, bbase, bcur, NB);
    bucket_scatter<<<nch, blk, 0, stream>>>(srows, scols, svals, bcur, tmp, E, NB);
    csr_place<<<NB, blk, 0, stream>>>(tmp, bbase, rowptr, packed, M, NB);

    // ---- network ----
    mfma_head<<<gm64, dim3(512), 0, stream>>>(feat_bf, Wt0, bf0, Wt1, bf1, x_bf, M);
    spmm_csr<<<(M + 3) / 4, blk, 0, stream>>>(rowptr, packed, x_bf, h_ws, M);
    mfma_ep<true,true,true,false,true,true,false,true,false><<<gm64,blk,0,stream>>>(
        h_ws, Wt7 /*Wg0 frag-major*/, nullptr, nullptr, x_bf, accf, nullptr, n0_bf, M);
    spmm_csr<<<(M + 3) / 4, blk, 0, stream>>>(rowptr, packed, n0_bf, h_ws, M);
    tail_fused<<<gm64, blk, 0, stream>>>(h_ws, accf, Wt7, bemb, bl, br, R0, R1, R2, M);
}

// Round 17
// 665.265 us; speedup vs baseline: 1.0967x; 1.0304x over previous
//
#include <hip/hip_runtime.h>
#include <math.h>

typedef short bf16x8 __attribute__((ext_vector_type(8)));
typedef float f32x4  __attribute__((ext_vector_type(4)));

__device__ __forceinline__ unsigned short f2bf(float x) {
    unsigned u = __float_as_uint(x);
    unsigned r = u + 0x7FFFu + ((u >> 16) & 1u);   // RNE
    return (unsigned short)(r >> 16);
}
__device__ __forceinline__ float bf2f(unsigned short b) {
    return __uint_as_float(((unsigned)b) << 16);
}
// tanh(x) = 1 - 2/(e^{2x}+1); v_exp_f32-based.
__device__ __forceinline__ float fast_tanh(float x) {
    float e = __expf(2.0f * x);
    return 1.0f - 2.0f / (e + 1.0f);
}

// ============ weight converts -> FRAGMENT-MAJOR layouts ============
// Layout D: chunk (kblk=k/32, cblk=c/64, n=c&3); lane = (c>>2)&15 | ((k>>3)&3)<<4; elem k&7.
__global__ __launch_bounds__(256)
void wconvD(const float* __restrict__ W, unsigned short* __restrict__ Wt, int K, int N)
{
    int id = blockIdx.x * 256 + threadIdx.x;
    if (id >= K * N) return;
    int c = id / K, k = id - c * K;
    int kblk = k >> 5, ksub = (k >> 3) & 3, kel = k & 7;
    int cblk = c >> 6, n = c & 3, lr = (c >> 2) & 15;
    int lane = lr + (ksub << 4);
    size_t dst = ((((size_t)kblk * (N >> 6) + cblk) * 4 + n) << 9) + (lane << 3) + kel;
    Wt[dst] = f2bf(W[(size_t)k * N + c]);
}

// Layout E (128-wide): chunk (ks=k/32, n=c&7); lane = (c>>3)&15 | ((k>>3)&3)<<4.
__global__ __launch_bounds__(256)
void wconv7(const float* __restrict__ Wg, const float* __restrict__ Wemb,
            const float* __restrict__ Wl, const float* __restrict__ Wr,
            unsigned short* __restrict__ dst)
{
    int id = blockIdx.x * 256 + threadIdx.x;    // < 7*16384
    if (id >= 7 * 16384) return;
    int m = id >> 14, r = id & 16383;
    int c = r >> 7, k = r & 127;
    const float* src = (m < 2) ? (Wg + m * 16384)
                     : (m == 2) ? Wemb
                     : (m < 5) ? (Wl + (m - 3) * 16384)
                               : (Wr + (m - 5) * 16384);
    int n = c & 7, lr = (c >> 3) & 15;
    int ks = k >> 5, ksub = (k >> 3) & 3, kel = k & 7;
    int lane = lr + (ksub << 4);
    dst[(size_t)m * 16384 + (((ks << 3) + n) << 9) + (lane << 3) + kel] = f2bf(src[(size_t)k * 128 + c]);
}

// ============ feat f32 -> bf16 in A-FRAGMENT-MAJOR layout A' ============
// Tile t = 16 rows. Element (row=t*16+r, k=kb*32+ksub*8+kel) stored at
//   featA[t*8192 + kb*512 + (ksub*16 + r)*8 + kel]   (lane = ksub*16+r)
// One thread per 16B chunk (fixed t,kb,ksub,r): reads 32B f32 contiguous,
// writes 16B; threads with consecutive r are contiguous in dst.
__global__ __launch_bounds__(256)
void f32_to_bf16A(const float* __restrict__ in, unsigned short* __restrict__ outA, int nchunks)
{
    int id = blockIdx.x * 256 + threadIdx.x;     // chunk index
    if (id >= nchunks) return;
    int t  = id >> 10;          // tile (1024 chunks per tile: 16 kb x 4 ksub x 16 r)
    int c  = id & 1023;
    int r  = c & 15;
    int ch = c >> 4;            // 0..63
    int kb = ch >> 2, ksub = ch & 3;
    const float* src = in + ((size_t)t * 16 + r) * 512 + kb * 32 + ksub * 8;
    float4 a = *(const float4*)src;
    float4 b = *(const float4*)(src + 4);
    unsigned short* dst = outA + (size_t)t * 8192 + kb * 512 + (ksub * 16 + r) * 8;
    *(ushort4*)dst       = make_ushort4(f2bf(a.x), f2bf(a.y), f2bf(a.z), f2bf(a.w));
    *(ushort4*)(dst + 4) = make_ushort4(f2bf(b.x), f2bf(b.y), f2bf(b.z), f2bf(b.w));
}

// ============ fused head: x = tanh( tanh(feat@Wf0+bf0) @ Wf1 + bf1 ) ============
// A in layout A' (fully coalesced fragment loads). 512 thr = 8 waves = 4 rg x 2 ch.
__global__ __launch_bounds__(512)
void mfma_head(const unsigned short* __restrict__ featA, const unsigned short* __restrict__ Wt0,
               const float* __restrict__ bf0, const unsigned short* __restrict__ Wt1,
               const float* __restrict__ bf1, unsigned short* __restrict__ x_bf, int M)
{
    __shared__ __align__(16) unsigned short x1s[4][16][264];   // 33.8 KB

    const int tid  = threadIdx.x;
    const int wv   = tid >> 6, lane = tid & 63;
    const int rg   = wv >> 1, ch = wv & 1;
    const int lr   = lane & 15;
    const int lk8  = (lane >> 4) * 8;
    const int rbase = (lane >> 4) * 4;
    const int tile = blockIdx.x * 4 + rg;
    const int row0 = tile * 16;

    // ---- stage 1: 16 rows x 128 cols (panels ch*2, ch*2+1) ----
    const unsigned short* aA  = featA + (size_t)tile * 8192 + (lane << 3);  // + kb*512
    const unsigned short* bb0 = Wt0 + ((((size_t)ch * 2) * 4) << 9) + (lane << 3);

    f32x4 acc1[8];
#pragma unroll
    for (int s = 0; s < 8; s++)
#pragma unroll
        for (int q = 0; q < 4; q++) acc1[s][q] = 0.f;

#pragma unroll 4
    for (int kb = 0; kb < 16; kb++) {
        bf16x8 af = *(const bf16x8*)(aA + kb * 512);
        bf16x8 bn[8];
        const unsigned short* bk = bb0 + (((size_t)kb * 16) << 9);
#pragma unroll
        for (int s = 0; s < 8; s++) bn[s] = *(const bf16x8*)(bk + ((size_t)s << 9));
#pragma unroll
        for (int s = 0; s < 8; s++)
            acc1[s] = __builtin_amdgcn_mfma_f32_16x16x32_bf16(af, bn[s], acc1[s], 0, 0, 0);
    }

    // epilogue 1 -> LDS (bf16)
#pragma unroll
    for (int cb = 0; cb < 2; cb++) {
        int colp = (ch * 2 + cb) * 64 + lr * 4;
        float4 b4 = *(const float4*)(bf0 + colp);
        float bv[4] = {b4.x, b4.y, b4.z, b4.w};
#pragma unroll
        for (int j = 0; j < 4; j++) {
            ushort4 o;
            o.x = f2bf(fast_tanh(acc1[cb * 4 + 0][j] + bv[0]));
            o.y = f2bf(fast_tanh(acc1[cb * 4 + 1][j] + bv[1]));
            o.z = f2bf(fast_tanh(acc1[cb * 4 + 2][j] + bv[2]));
            o.w = f2bf(fast_tanh(acc1[cb * 4 + 3][j] + bv[3]));
            *(ushort4*)&x1s[rg][rbase + j][colp] = o;
        }
    }
    __syncthreads();

    // ---- stage 2: 16 rows x 64 cols (panel ch) from LDS A-frags ----
    const unsigned short* bb1 = Wt1 + ((((size_t)ch) * 4) << 9) + (lane << 3);

    f32x4 acc2[4];
#pragma unroll
    for (int n = 0; n < 4; n++)
#pragma unroll
        for (int q = 0; q < 4; q++) acc2[n][q] = 0.f;

#pragma unroll 4
    for (int ks = 0; ks < 8; ks++) {
        bf16x8 af = *(const bf16x8*)&x1s[rg][lr][ks * 32 + lk8];
        bf16x8 bn[4];
        const unsigned short* bk = bb1 + (((size_t)ks * 8) << 9);
#pragma unroll
        for (int n = 0; n < 4; n++) bn[n] = *(const bf16x8*)(bk + ((size_t)n << 9));
#pragma unroll
        for (int n = 0; n < 4; n++)
            acc2[n] = __builtin_amdgcn_mfma_f32_16x16x32_bf16(af, bn[n], acc2[n], 0, 0, 0);
    }

    const int cbase = ch * 64 + lr * 4;
    float4 b4 = *(const float4*)(bf1 + cbase);
    float bv[4] = {b4.x, b4.y, b4.z, b4.w};
#pragma unroll
    for (int j = 0; j < 4; j++) {
        int row = row0 + rbase + j;
        if (row < M) {
            ushort4 o;
            o.x = f2bf(fast_tanh(acc2[0][j] + bv[0]));
            o.y = f2bf(fast_tanh(acc2[1][j] + bv[1]));
            o.z = f2bf(fast_tanh(acc2[2][j] + bv[2]));
            o.w = f2bf(fast_tanh(acc2[3][j] + bv[3]));
            *(ushort4*)(x_bf + ((size_t)row << 7) + cbase) = o;
        }
    }
}

// ============ MFMA K=128 single-tile, fragment-major B, fused epilogue (s4) ============
template<bool ABF16, bool TANH, bool L2, bool RESID, bool AUX, bool AUXBF,
         bool F32OUT, bool BF16OUT, bool BIAS>
__global__ __launch_bounds__(256, 4)
void mfma_ep(const void* __restrict__ A_, const unsigned short* __restrict__ Wt,
             const float* __restrict__ bias, const unsigned short* __restrict__ resid_bf,
             const void* __restrict__ aux_in, float* __restrict__ aux_out,
             float* __restrict__ out, unsigned short* __restrict__ out_bf, int M)
{
    const int tid  = threadIdx.x;
    const int row0 = blockIdx.x * 64;
    const int wv   = tid >> 6, lane = tid & 63;
    const int lr   = lane & 15;
    const int lk8  = (lane >> 4) * 8;
    const int wr   = wv * 16;

    const unsigned short* Abr;
    const float*          Afr;
    {
        int r = row0 + wr + lr;
        r = r < M ? r : (M - 1);
        Abr = (const unsigned short*)A_ + ((size_t)r << 7) + lk8;
        Afr = (const float*)A_          + ((size_t)r << 7) + lk8;
    }
    const unsigned short* wb = Wt + (lane << 3);

    f32x4 acc[8];
#pragma unroll
    for (int n = 0; n < 8; n++)
#pragma unroll
        for (int j = 0; j < 4; j++) acc[n][j] = 0.f;

#pragma unroll 2
    for (int ks = 0; ks < 4; ks++) {
        bf16x8 af, bn[8];
        if (ABF16) af = *(const bf16x8*)(Abr + ks * 32);
        else {
            float4 a = *(const float4*)(Afr + ks * 32);
            float4 b = *(const float4*)(Afr + ks * 32 + 4);
            af[0]=(short)f2bf(a.x); af[1]=(short)f2bf(a.y); af[2]=(short)f2bf(a.z); af[3]=(short)f2bf(a.w);
            af[4]=(short)f2bf(b.x); af[5]=(short)f2bf(b.y); af[6]=(short)f2bf(b.z); af[7]=(short)f2bf(b.w);
        }
#pragma unroll
        for (int n = 0; n < 8; n++)
            bn[n] = *(const bf16x8*)(wb + ((((ks << 3) + n)) << 9));
#pragma unroll
        for (int n = 0; n < 8; n++)
            acc[n] = __builtin_amdgcn_mfma_f32_16x16x32_bf16(af, bn[n], acc[n], 0, 0, 0);
    }

    const int cbase = lr * 8;
    float bv[8];
    if (BIAS) {
        float4 b0 = *(const float4*)(bias + cbase);
        float4 b1 = *(const float4*)(bias + cbase + 4);
        bv[0]=b0.x; bv[1]=b0.y; bv[2]=b0.z; bv[3]=b0.w;
        bv[4]=b1.x; bv[5]=b1.y; bv[6]=b1.z; bv[7]=b1.w;
    } else {
#pragma unroll
        for (int n = 0; n < 8; n++) bv[n] = 0.f;
    }
    const int rbase = (lane >> 4) * 4;

#pragma unroll
    for (int j = 0; j < 4; j++) {
        int row = row0 + wr + rbase + j;
        bool ok = row < M;
        size_t base = ((size_t)row << 7) + cbase;
        float v[8];
#pragma unroll
        for (int n = 0; n < 8; n++) {
            v[n] = acc[n][j] + bv[n];
            if (TANH) v[n] = fast_tanh(v[n]);
        }
        if (RESID) {
            if (ok) {
                bf16x8 rv = *(const bf16x8*)(resid_bf + base);
#pragma unroll
                for (int n = 0; n < 8; n++) v[n] += bf2f((unsigned short)rv[n]);
            }
        }
        if (L2) {
            float s = 0.f;
#pragma unroll
            for (int n = 0; n < 8; n++) s += v[n] * v[n];
#pragma unroll
            for (int msk = 8; msk >= 1; msk >>= 1) s += __shfl_xor(s, msk);
            float sc = 1.f / fmaxf(sqrtf(s), 1e-12f);
#pragma unroll
            for (int n = 0; n < 8; n++) v[n] *= sc;
        }
        if (ok) {
            if (F32OUT) {
                *(float4*)(out + base)     = make_float4(v[0], v[1], v[2], v[3]);
                *(float4*)(out + base + 4) = make_float4(v[4], v[5], v[6], v[7]);
            }
            if (BF16OUT) {
                bf16x8 o;
#pragma unroll
                for (int n = 0; n < 8; n++) o[n] = (short)f2bf(v[n]);
                *(bf16x8*)(out_bf + base) = o;
            }
            if (AUX) {
                float ai[8];
                if (AUXBF) {
                    bf16x8 av = *(const bf16x8*)((const unsigned short*)aux_in + base);
#pragma unroll
                    for (int n = 0; n < 8; n++) ai[n] = bf2f((unsigned short)av[n]);
                } else {
                    float4 a0 = *(const float4*)((const float*)aux_in + base);
                    float4 a1 = *(const float4*)((const float*)aux_in + base + 4);
                    ai[0]=a0.x; ai[1]=a0.y; ai[2]=a0.z; ai[3]=a0.w;
                    ai[4]=a1.x; ai[5]=a1.y; ai[6]=a1.z; ai[7]=a1.w;
                }
                *(float4*)(aux_out + base)     = make_float4(ai[0]+v[0], ai[1]+v[1], ai[2]+v[2], ai[3]+v[3]);
                *(float4*)(aux_out + base + 4) = make_float4(ai[4]+v[4], ai[5]+v[5], ai[6]+v[6], ai[7]+v[7]);
            }
        }
    }
}

// ============ fused tail (fragment-major weights) ============
__global__ __launch_bounds__(256, 4)
void tail_fused(const unsigned short* __restrict__ h_bf, const float* __restrict__ accf,
                const unsigned short* __restrict__ Wt7,
                const float* __restrict__ bemb, const float* __restrict__ bl,
                const float* __restrict__ br,
                float* __restrict__ embO, float* __restrict__ lftO,
                float* __restrict__ rgtO, int M)
{
    __shared__ __align__(16) unsigned short ldsA[4][16][136];  // n1
    __shared__ __align__(16) unsigned short ldsB[4][16][136];  // acc / lft0 / rgt0

    const int tid = threadIdx.x;
    const int wv = tid >> 6, lane = tid & 63;
    const int lr = lane & 15;
    const int lk8 = (lane >> 4) * 8;
    const int rbase = (lane >> 4) * 4;
    const int row0 = blockIdx.x * 64 + wv * 16;
    const int cbase = lr * 8;

    const unsigned short* Wg1t  = Wt7 + 1 * 16384 + (lane << 3);
    const unsigned short* Wembt = Wt7 + 2 * 16384 + (lane << 3);
    const unsigned short* Wl0t  = Wt7 + 3 * 16384 + (lane << 3);
    const unsigned short* Wl1t  = Wt7 + 4 * 16384 + (lane << 3);
    const unsigned short* Wr0t  = Wt7 + 5 * 16384 + (lane << 3);
    const unsigned short* Wr1t  = Wt7 + 6 * 16384 + (lane << 3);

    f32x4 acc[8];

#define ZACC() { _Pragma("unroll") for (int n = 0; n < 8; n++) \
                 _Pragma("unroll") for (int q = 0; q < 4; q++) acc[n][q] = 0.f; }
#define MM128(AFRAG, WPTR)                                                            \
    _Pragma("unroll")                                                                 \
    for (int ks = 0; ks < 4; ks++) {                                                  \
        bf16x8 af = (AFRAG);                                                          \
        bf16x8 bn[8];                                                                 \
        _Pragma("unroll")                                                             \
        for (int n = 0; n < 8; n++)                                                   \
            bn[n] = *(const bf16x8*)((WPTR) + ((((ks << 3) + n)) << 9));              \
        _Pragma("unroll")                                                             \
        for (int n = 0; n < 8; n++)                                                   \
            acc[n] = __builtin_amdgcn_mfma_f32_16x16x32_bf16(af, bn[n], acc[n], 0, 0, 0); \
    }
#define LDBIAS(BV, P) { float4 b0_ = *(const float4*)((P) + cbase);                   \
                        float4 b1_ = *(const float4*)((P) + cbase + 4);               \
                        BV[0]=b0_.x; BV[1]=b0_.y; BV[2]=b0_.z; BV[3]=b0_.w;           \
                        BV[4]=b1_.x; BV[5]=b1_.y; BV[6]=b1_.z; BV[7]=b1_.w; }
#define L2NORM(V) { float s_ = 0.f;                                                   \
                    _Pragma("unroll") for (int n = 0; n < 8; n++) s_ += V[n]*V[n];    \
                    _Pragma("unroll") for (int mk = 8; mk >= 1; mk >>= 1) s_ += __shfl_xor(s_, mk); \
                    float sc_ = 1.f / fmaxf(sqrtf(s_), 1e-12f);                       \
                    _Pragma("unroll") for (int n = 0; n < 8; n++) V[n] *= sc_; }

    // ---- stage 1: n1 = l2norm(tanh(h @ Wg1)); acc = accf + n1 ----
    const unsigned short* hrow;
    {
        int r = row0 + lr;
        r = r < M ? r : (M - 1);
        hrow = h_bf + ((size_t)r << 7) + lk8;
    }
    ZACC();
    MM128(*(const bf16x8*)(hrow + ks * 32), Wg1t);
#pragma unroll
    for (int j = 0; j < 4; j++) {
        int row = row0 + rbase + j;
        int rc = row < M ? row : (M - 1);
        float v[8];
#pragma unroll
        for (int n = 0; n < 8; n++) v[n] = fast_tanh(acc[n][j]);
        L2NORM(v);
        bf16x8 o;
#pragma unroll
        for (int n = 0; n < 8; n++) o[n] = (short)f2bf(v[n]);
        *(bf16x8*)&ldsA[wv][rbase + j][cbase] = o;
        float4 a0 = *(const float4*)(accf + ((size_t)rc << 7) + cbase);
        float4 a1 = *(const float4*)(accf + ((size_t)rc << 7) + cbase + 4);
        float av[8] = {a0.x+v[0], a0.y+v[1], a0.z+v[2], a0.w+v[3],
                       a1.x+v[4], a1.y+v[5], a1.z+v[6], a1.w+v[7]};
        bf16x8 ob;
#pragma unroll
        for (int n = 0; n < 8; n++) ob[n] = (short)f2bf(av[n]);
        *(bf16x8*)&ldsB[wv][rbase + j][cbase] = ob;
    }

    // ---- stage 2: emb = l2norm(acc @ Wemb + bemb) ----
    ZACC();
    MM128(*(const bf16x8*)&ldsB[wv][lr][ks * 32 + lk8], Wembt);
    {
        float bv[8]; LDBIAS(bv, bemb);
#pragma unroll
        for (int j = 0; j < 4; j++) {
            int row = row0 + rbase + j;
            float v[8];
#pragma unroll
            for (int n = 0; n < 8; n++) v[n] = acc[n][j] + bv[n];
            L2NORM(v);
            if (row < M) {
                size_t base = ((size_t)row << 7) + cbase;
                *(float4*)(embO + base)     = make_float4(v[0], v[1], v[2], v[3]);
                *(float4*)(embO + base + 4) = make_float4(v[4], v[5], v[6], v[7]);
            }
        }
    }

    // ---- stage 3: lft0 = tanh(n1 @ Wl0 + bl0) + n1 ----
    ZACC();
    MM128(*(const bf16x8*)&ldsA[wv][lr][ks * 32 + lk8], Wl0t);
    {
        float bv[8]; LDBIAS(bv, bl);
#pragma unroll
        for (int j = 0; j < 4; j++) {
            bf16x8 rv = *(const bf16x8*)&ldsA[wv][rbase + j][cbase];
            bf16x8 ob;
#pragma unroll
            for (int n = 0; n < 8; n++)
                ob[n] = (short)f2bf(fast_tanh(acc[n][j] + bv[n]) + bf2f((unsigned short)rv[n]));
            *(bf16x8*)&ldsB[wv][rbase + j][cbase] = ob;
        }
    }

    // ---- stage 4: lft = tanh(lft0 @ Wl1 + bl1) ----
    ZACC();
    MM128(*(const bf16x8*)&ldsB[wv][lr][ks * 32 + lk8], Wl1t);
    {
        float bv[8]; LDBIAS(bv, bl + 128);
#pragma unroll
        for (int j = 0; j < 4; j++) {
            int row = row0 + rbase + j;
            if (row < M) {
                size_t base = ((size_t)row << 7) + cbase;
                *(float4*)(lftO + base)     = make_float4(fast_tanh(acc[0][j]+bv[0]), fast_tanh(acc[1][j]+bv[1]),
                                                          fast_tanh(acc[2][j]+bv[2]), fast_tanh(acc[3][j]+bv[3]));
                *(float4*)(lftO + base + 4) = make_float4(fast_tanh(acc[4][j]+bv[4]), fast_tanh(acc[5][j]+bv[5]),
                                                          fast_tanh(acc[6][j]+bv[6]), fast_tanh(acc[7][j]+bv[7]));
            }
        }
    }

    // ---- stage 5: rgt0 = tanh(n1 @ Wr0 + br0) + n1 ----
    ZACC();
    MM128(*(const bf16x8*)&ldsA[wv][lr][ks * 32 + lk8], Wr0t);
    {
        float bv[8]; LDBIAS(bv, br);
#pragma unroll
        for (int j = 0; j < 4; j++) {
            bf16x8 rv = *(const bf16x8*)&ldsA[wv][rbase + j][cbase];
            bf16x8 ob;
#pragma unroll
            for (int n = 0; n < 8; n++)
                ob[n] = (short)f2bf(fast_tanh(acc[n][j] + bv[n]) + bf2f((unsigned short)rv[n]));
            *(bf16x8*)&ldsB[wv][rbase + j][cbase] = ob;
        }
    }

    // ---- stage 6: rgt = tanh(rgt0 @ Wr1 + br1) ----
    ZACC();
    MM128(*(const bf16x8*)&ldsB[wv][lr][ks * 32 + lk8], Wr1t);
    {
        float bv[8]; LDBIAS(bv, br + 128);
#pragma unroll
        for (int j = 0; j < 4; j++) {
            int row = row0 + rbase + j;
            if (row < M) {
                size_t base = ((size_t)row << 7) + cbase;
                *(float4*)(rgtO + base)     = make_float4(fast_tanh(acc[0][j]+bv[0]), fast_tanh(acc[1][j]+bv[1]),
                                                          fast_tanh(acc[2][j]+bv[2]), fast_tanh(acc[3][j]+bv[3]));
                *(float4*)(rgtO + base + 4) = make_float4(fast_tanh(acc[4][j]+bv[4]), fast_tanh(acc[5][j]+bv[5]),
                                                          fast_tanh(acc[6][j]+bv[6]), fast_tanh(acc[7][j]+bv[7]));
            }
        }
    }
#undef ZACC
#undef MM128
#undef LDBIAS
#undef L2NORM
}

// ============ bucketed CSR build ============
#define RCHUNK 16384

__global__ __launch_bounds__(256)
void bhist_k(const int* __restrict__ rows, int* __restrict__ bcnt, int E, int NB)
{
    __shared__ int lc[1024];
    for (int b = threadIdx.x; b < NB; b += 256) lc[b] = 0;
    __syncthreads();
    int start = blockIdx.x * RCHUNK;
    int end = min(start + RCHUNK, E);
    for (int i = start + threadIdx.x; i < end; i += 256)
        atomicAdd(&lc[rows[i] >> 7], 1);
    __syncthreads();
    for (int b = threadIdx.x; b < NB; b += 256)
        if (lc[b]) atomicAdd(&bcnt[b], lc[b]);
}

__global__ __launch_bounds__(256)
void bucket_scan(const int* __restrict__ bcnt, int* __restrict__ bbase,
                 int* __restrict__ bcur, int NB)
{
    __shared__ int sdata[256];
    const int tid = threadIdx.x;
    int loc[4]; int s = 0;
#pragma unroll
    for (int j = 0; j < 4; j++) {
        int i = tid * 4 + j;
        int v = (i < NB) ? bcnt[i] : 0;
        loc[j] = s; s += v;
    }
    sdata[tid] = s;
    __syncthreads();
    int x = s;
    for (int off = 1; off < 256; off <<= 1) {
        int t = 0;
        if (tid >= off) t = sdata[tid - off];
        __syncthreads();
        x += t;
        sdata[tid] = x;
        __syncthreads();
    }
    int excl = x - s;
#pragma unroll
    for (int j = 0; j < 4; j++) {
        int i = tid * 4 + j;
        if (i < NB) { bbase[i] = excl + loc[j]; bcur[i] = excl + loc[j]; }
    }
    if (tid == 255) bbase[NB] = x;
}

__global__ __launch_bounds__(256)
void bucket_scatter(const int* __restrict__ rows, const int* __restrict__ cols,
                    const float* __restrict__ vals, int* __restrict__ bcur,
                    int2* __restrict__ tmp, int E, int NB)
{
    __shared__ int lcnt[1024];
    __shared__ int lbase[1024];
    for (int b = threadIdx.x; b < NB; b += 256) lcnt[b] = 0;
    __syncthreads();
    int start = blockIdx.x * RCHUNK;
    int end = min(start + RCHUNK, E);
    for (int i = start + threadIdx.x; i < end; i += 256)
        atomicAdd(&lcnt[rows[i] >> 7], 1);
    __syncthreads();
    for (int b = threadIdx.x; b < NB; b += 256) {
        int c = lcnt[b];
        lbase[b] = c ? atomicAdd(&bcur[b], c) : 0;
        lcnt[b] = 0;
    }
    __syncthreads();
    for (int i = start + threadIdx.x; i < end; i += 256) {
        int r = rows[i];
        int b = r >> 7;
        int off = atomicAdd(&lcnt[b], 1);
        tmp[lbase[b] + off] = make_int2(cols[i] | ((r & 127) << 17), __float_as_int(vals[i]));
    }
}

__global__ __launch_bounds__(256)
void csr_place(const int2* __restrict__ tmp, const int* __restrict__ bbase,
               int* __restrict__ rowptr, int2* __restrict__ packed, int M, int NB)
{
    __shared__ int lcnt[128];
    __shared__ int lofs[128];
    const int tid = threadIdx.x;
    const int b = blockIdx.x;
    const int s = bbase[b], e = bbase[b + 1];
    const int rb = b << 7;
    if (tid < 128) lcnt[tid] = 0;
    __syncthreads();
    for (int i = s + tid; i < e; i += 256)
        atomicAdd(&lcnt[(((unsigned)tmp[i].x) >> 17) & 127], 1);
    __syncthreads();
    if (tid == 0) {
        int run = s;
#pragma unroll 8
        for (int r = 0; r < 128; r++) { lofs[r] = run; run += lcnt[r]; }
    }
    __syncthreads();
    if (tid < 128 && rb + tid < M) rowptr[rb + tid] = lofs[tid];
    if (b == NB - 1 && tid == 0) rowptr[M] = e;
    if (tid < 128) lcnt[tid] = 0;
    __syncthreads();
    for (int i = s + tid; i < e; i += 256) {
        int2 t = tmp[i];
        int rl = (((unsigned)t.x) >> 17) & 127;
        int pos = lofs[rl] + atomicAdd(&lcnt[rl], 1);
        packed[pos] = make_int2(t.x & 0x1FFFF, t.y);
    }
}

// ============ CSR SpMM: 16 lanes/edge x 4 edge-groups, 16B gathers ============
__global__ __launch_bounds__(256)
void spmm_csr(const int* __restrict__ rowptr, const int2* __restrict__ packed,
              const unsigned short* __restrict__ embb, unsigned short* __restrict__ hb, int N)
{
    const int wv = threadIdx.x >> 6, lane = threadIdx.x & 63;
    const int g = lane >> 4, q = lane & 15;
    const int r = blockIdx.x * 4 + wv;
    if (r >= N) return;
    const int s = rowptr[r], e = rowptr[r + 1];
    const unsigned short* __restrict__ eb = embb + q * 8;

    float a0=0.f,a1=0.f,a2=0.f,a3=0.f,a4=0.f,a5=0.f,a6=0.f,a7=0.f;
    int i = s + g;
    for (; i + 12 < e; i += 16) {
#pragma unroll
        for (int u = 0; u < 4; u++) {
            int2 p = packed[i + 4 * u];
            uint4 m = *(const uint4*)(eb + ((size_t)p.x << 7));
            float v = __int_as_float(p.y);
            a0 += v * __uint_as_float(m.x << 16);
            a1 += v * __uint_as_float(m.x & 0xffff0000u);
            a2 += v * __uint_as_float(m.y << 16);
            a3 += v * __uint_as_float(m.y & 0xffff0000u);
            a4 += v * __uint_as_float(m.z << 16);
            a5 += v * __uint_as_float(m.z & 0xffff0000u);
            a6 += v * __uint_as_float(m.w << 16);
            a7 += v * __uint_as_float(m.w & 0xffff0000u);
        }
    }
    for (; i < e; i += 4) {
        int2 p = packed[i];
        uint4 m = *(const uint4*)(eb + ((size_t)p.x << 7));
        float v = __int_as_float(p.y);
        a0 += v * __uint_as_float(m.x << 16);
        a1 += v * __uint_as_float(m.x & 0xffff0000u);
        a2 += v * __uint_as_float(m.y << 16);
        a3 += v * __uint_as_float(m.y & 0xffff0000u);
        a4 += v * __uint_as_float(m.z << 16);
        a5 += v * __uint_as_float(m.z & 0xffff0000u);
        a6 += v * __uint_as_float(m.w << 16);
        a7 += v * __uint_as_float(m.w & 0xffff0000u);
    }
#pragma unroll
    for (int msk = 16; msk <= 32; msk <<= 1) {
        a0 += __shfl_xor(a0, msk); a1 += __shfl_xor(a1, msk);
        a2 += __shfl_xor(a2, msk); a3 += __shfl_xor(a3, msk);
        a4 += __shfl_xor(a4, msk); a5 += __shfl_xor(a5, msk);
        a6 += __shfl_xor(a6, msk); a7 += __shfl_xor(a7, msk);
    }
    if (g == 0) {
        unsigned o0 = (unsigned)f2bf(a0) | ((unsigned)f2bf(a1) << 16);
        unsigned o1 = (unsigned)f2bf(a2) | ((unsigned)f2bf(a3) << 16);
        unsigned o2 = (unsigned)f2bf(a4) | ((unsigned)f2bf(a5) << 16);
        unsigned o3 = (unsigned)f2bf(a6) | ((unsigned)f2bf(a7) << 16);
        *(uint4*)(hb + ((size_t)r << 7) + q * 8) = make_uint4(o0, o1, o2, o3);
    }
}

// ============ launch ============
extern "C" void kernel_launch(void* const* d_in, const int* in_sizes, int n_in,
                              void* d_out, int out_size, void* d_ws, size_t ws_size,
                              hipStream_t stream)
{
    const float* feat  = (const float*)d_in[0];
    const int*   srows = (const int*)  d_in[1];
    const int*   scols = (const int*)  d_in[2];
    const float* svals = (const float*)d_in[3];
    const float* Wf0   = (const float*)d_in[4];
    const float* bf0   = (const float*)d_in[5];
    const float* Wf1   = (const float*)d_in[6];
    const float* bf1   = (const float*)d_in[7];
    const float* Wg    = (const float*)d_in[8];
    const float* Wemb  = (const float*)d_in[9];
    const float* bemb  = (const float*)d_in[10];
    const float* Wl    = (const float*)d_in[11];
    const float* bl    = (const float*)d_in[12];
    const float* Wr    = (const float*)d_in[13];
    const float* br    = (const float*)d_in[14];

    const int M = in_sizes[0] / 512;   // 100000 nodes (divisible by 16)
    const int E = in_sizes[1];         // 3200000 edges
    const int NB = (M + 127) >> 7;     // 782 buckets
    const int NT = (M + 15) >> 4;      // 6250 row-tiles

    float* out = (float*)d_out;
    float* R0 = out;
    float* R1 = out + (size_t)M * 128;
    float* R2 = out + (size_t)M * 256;

    // ---- ws layout ----
    float* ws = (float*)d_ws;
    float* accf = ws;                                      // [M,128] f32; tmp aliases (dead before s4)
    int2*  tmp  = (int2*)ws;
    int*   ip = (int*)(ws + (size_t)M * 128);
    int*   rowptr  = ip;                                   // M+1
    int2*  packed  = (int2*)(ip + (((size_t)M + 4) & ~(size_t)3));  // E
    int*   bcnt    = (int*)(packed + E);                   // 1024
    int*   bbase   = bcnt + 1024;                          // 1032
    int*   bcur    = bbase + 1032;                         // 1024
    unsigned short* h_ws = (unsigned short*)(bcur + 1024); // [M,128] bf16 spmm accumulator
    unsigned short* Wt0  = h_ws + (size_t)M * 128;         // [512x256] frag-major D
    unsigned short* Wt1  = Wt0 + 256 * 512;                // [256x128] frag-major D
    unsigned short* Wt7  = Wt1 + 128 * 256;                // 7 x [128x128] frag-major E

    // ---- d_out scratch timeline ----
    unsigned short* R1a = (unsigned short*)R1;
    unsigned short* featA = (unsigned short*)R0;   // [NT*8192] bf16 A'-layout, dead after head
    unsigned short* x_bf  = (unsigned short*)R2;   // head out; spmm3 src; s4 aux (dead before tail)
    unsigned short* n0_bf = R1a;                   // s4 -> spmm5

    dim3 blk(256);
    const int gm64 = (M + 63) / 64;
    const int nch  = (E + RCHUNK - 1) / RCHUNK;
    const int nchunks = NT * 1024;

    // weight converts
    wconvD<<<(512*256 + 255)/256, blk, 0, stream>>>(Wf0, Wt0, 512, 256);
    wconvD<<<(256*128 + 255)/256, blk, 0, stream>>>(Wf1, Wt1, 256, 128);
    wconv7<<<(7*16384 + 255)/256, blk, 0, stream>>>(Wg, Wemb, Wl, Wr, Wt7);

    // feat -> bf16 A'-layout (into R0+R1 region)
    f32_to_bf16A<<<(nchunks + 255)/256, blk, 0, stream>>>(feat, featA, nchunks);

    // ---- CSR build ----
    hipMemsetAsync(bcnt, 0, (size_t)NB * 4, stream);
    bhist_k<<<nch, blk, 0, stream>>>(srows, bcnt, E, NB);
    bucket_scan<<<1, blk, 0, stream>>>(bcnt, bbase, bcur, NB);
    bucket_scatter<<<nch, blk, 0, stream>>>(srows, scols, svals, bcur, tmp, E, NB);
    csr_place<<<NB, blk, 0, stream>>>(tmp, bbase, rowptr, packed, M, NB);

    // ---- network ----
    mfma_head<<<gm64, dim3(512), 0, stream>>>(featA, Wt0, bf0, Wt1, bf1, x_bf, M);
    spmm_csr<<<(M + 3) / 4, blk, 0, stream>>>(rowptr, packed, x_bf, h_ws, M);
    mfma_ep<true,true,true,false,true,true,false,true,false><<<gm64,blk,0,stream>>>(
        h_ws, Wt7 /*Wg0 frag-major*/, nullptr, nullptr, x_bf, accf, nullptr, n0_bf, M);
    spmm_csr<<<(M + 3) / 4, blk, 0, stream>>>(rowptr, packed, n0_bf, h_ws, M);
    tail_fused<<<gm64, blk, 0, stream>>>(h_ws, accf, Wt7, bemb, bl, br, R0, R1, R2, M);
}

// Round 18
// 639.367 us; speedup vs baseline: 1.1411x; 1.0405x over previous
//
#include <hip/hip_runtime.h>
#include <math.h>

typedef short bf16x8 __attribute__((ext_vector_type(8)));
typedef float f32x4  __attribute__((ext_vector_type(4)));

__device__ __forceinline__ unsigned short f2bf(float x) {
    unsigned u = __float_as_uint(x);
    unsigned r = u + 0x7FFFu + ((u >> 16) & 1u);   // RNE
    return (unsigned short)(r >> 16);
}
__device__ __forceinline__ float bf2f(unsigned short b) {
    return __uint_as_float(((unsigned)b) << 16);
}
__device__ __forceinline__ float fast_tanh(float x) {
    float e = __expf(2.0f * x);
    return 1.0f - 2.0f / (e + 1.0f);
}

// ============ weight converts -> FRAGMENT-MAJOR layouts ============
__global__ __launch_bounds__(256)
void wconvD(const float* __restrict__ W, unsigned short* __restrict__ Wt, int K, int N)
{
    int id = blockIdx.x * 256 + threadIdx.x;
    if (id >= K * N) return;
    int c = id / K, k = id - c * K;
    int kblk = k >> 5, ksub = (k >> 3) & 3, kel = k & 7;
    int cblk = c >> 6, n = c & 3, lr = (c >> 2) & 15;
    int lane = lr + (ksub << 4);
    size_t dst = ((((size_t)kblk * (N >> 6) + cblk) * 4 + n) << 9) + (lane << 3) + kel;
    Wt[dst] = f2bf(W[(size_t)k * N + c]);
}

__global__ __launch_bounds__(256)
void wconv7(const float* __restrict__ Wg, const float* __restrict__ Wemb,
            const float* __restrict__ Wl, const float* __restrict__ Wr,
            unsigned short* __restrict__ dst)
{
    int id = blockIdx.x * 256 + threadIdx.x;    // < 7*16384
    if (id >= 7 * 16384) return;
    int m = id >> 14, r = id & 16383;
    int c = r >> 7, k = r & 127;
    const float* src = (m < 2) ? (Wg + m * 16384)
                     : (m == 2) ? Wemb
                     : (m < 5) ? (Wl + (m - 3) * 16384)
                               : (Wr + (m - 5) * 16384);
    int n = c & 7, lr = (c >> 3) & 15;
    int ks = k >> 5, ksub = (k >> 3) & 3, kel = k & 7;
    int lane = lr + (ksub << 4);
    dst[(size_t)m * 16384 + (((ks << 3) + n) << 9) + (lane << 3) + kel] = f2bf(src[(size_t)k * 128 + c]);
}

// ============ feat f32 -> bf16 in A-FRAGMENT-MAJOR layout A' ============
__global__ __launch_bounds__(256)
void f32_to_bf16A(const float* __restrict__ in, unsigned short* __restrict__ outA, int nchunks)
{
    int id = blockIdx.x * 256 + threadIdx.x;
    if (id >= nchunks) return;
    int t  = id >> 10;
    int c  = id & 1023;
    int r  = c & 15;
    int ch = c >> 4;
    int kb = ch >> 2, ksub = ch & 3;
    const float* src = in + ((size_t)t * 16 + r) * 512 + kb * 32 + ksub * 8;
    float4 a = *(const float4*)src;
    float4 b = *(const float4*)(src + 4);
    unsigned short* dst = outA + (size_t)t * 8192 + kb * 512 + (ksub * 16 + r) * 8;
    *(ushort4*)dst       = make_ushort4(f2bf(a.x), f2bf(a.y), f2bf(a.z), f2bf(a.w));
    *(ushort4*)(dst + 4) = make_ushort4(f2bf(b.x), f2bf(b.y), f2bf(b.z), f2bf(b.w));
}

// ============ fused head, 2 row-tiles per wave (M-register-blocked) ============
// Block = 128 rows (8 tiles); 8 waves = 4 rg x 2 ch; wave handles tiles rg*2, rg*2+1.
__global__ __launch_bounds__(512, 2)
void mfma_head(const unsigned short* __restrict__ featA, const unsigned short* __restrict__ Wt0,
               const float* __restrict__ bf0, const unsigned short* __restrict__ Wt1,
               const float* __restrict__ bf1, unsigned short* __restrict__ x_bf, int M)
{
    __shared__ __align__(16) unsigned short x1s[8][16][264];   // 67.6 KB

    const int tid  = threadIdx.x;
    const int wv   = tid >> 6, lane = tid & 63;
    const int rg   = wv >> 1, ch = wv & 1;
    const int lr   = lane & 15;
    const int lk8  = (lane >> 4) * 8;
    const int rbase = (lane >> 4) * 4;
    const int tile0 = blockIdx.x * 8 + rg * 2;      // + t for t in {0,1}

    // ---- stage 1: 2 tiles x 16 rows x 128 cols (panels ch*2, ch*2+1) ----
    const unsigned short* aA0 = featA + (size_t)tile0 * 8192 + (lane << 3);
    const unsigned short* aA1 = aA0 + 8192;
    const unsigned short* bb0 = Wt0 + ((((size_t)ch * 2) * 4) << 9) + (lane << 3);

    f32x4 acc1[2][8];
#pragma unroll
    for (int t = 0; t < 2; t++)
#pragma unroll
        for (int s = 0; s < 8; s++)
#pragma unroll
            for (int q = 0; q < 4; q++) acc1[t][s][q] = 0.f;

#pragma unroll 2
    for (int kb = 0; kb < 16; kb++) {
        bf16x8 af0 = *(const bf16x8*)(aA0 + kb * 512);
        bf16x8 af1 = *(const bf16x8*)(aA1 + kb * 512);
        bf16x8 bn[8];
        const unsigned short* bk = bb0 + (((size_t)kb * 16) << 9);
#pragma unroll
        for (int s = 0; s < 8; s++) bn[s] = *(const bf16x8*)(bk + ((size_t)s << 9));
#pragma unroll
        for (int s = 0; s < 8; s++) {
            acc1[0][s] = __builtin_amdgcn_mfma_f32_16x16x32_bf16(af0, bn[s], acc1[0][s], 0, 0, 0);
            acc1[1][s] = __builtin_amdgcn_mfma_f32_16x16x32_bf16(af1, bn[s], acc1[1][s], 0, 0, 0);
        }
    }

    // epilogue 1 -> LDS (bf16)
#pragma unroll
    for (int t = 0; t < 2; t++) {
#pragma unroll
        for (int cb = 0; cb < 2; cb++) {
            int colp = (ch * 2 + cb) * 64 + lr * 4;
            float4 b4 = *(const float4*)(bf0 + colp);
            float bv[4] = {b4.x, b4.y, b4.z, b4.w};
#pragma unroll
            for (int j = 0; j < 4; j++) {
                ushort4 o;
                o.x = f2bf(fast_tanh(acc1[t][cb * 4 + 0][j] + bv[0]));
                o.y = f2bf(fast_tanh(acc1[t][cb * 4 + 1][j] + bv[1]));
                o.z = f2bf(fast_tanh(acc1[t][cb * 4 + 2][j] + bv[2]));
                o.w = f2bf(fast_tanh(acc1[t][cb * 4 + 3][j] + bv[3]));
                *(ushort4*)&x1s[rg * 2 + t][rbase + j][colp] = o;
            }
        }
    }
    __syncthreads();

    // ---- stage 2: 2 tiles x 16 rows x 64 cols (panel ch) from LDS ----
    const unsigned short* bb1 = Wt1 + ((((size_t)ch) * 4) << 9) + (lane << 3);

    f32x4 acc2[2][4];
#pragma unroll
    for (int t = 0; t < 2; t++)
#pragma unroll
        for (int n = 0; n < 4; n++)
#pragma unroll
            for (int q = 0; q < 4; q++) acc2[t][n][q] = 0.f;

#pragma unroll 2
    for (int ks = 0; ks < 8; ks++) {
        bf16x8 af0 = *(const bf16x8*)&x1s[rg * 2 + 0][lr][ks * 32 + lk8];
        bf16x8 af1 = *(const bf16x8*)&x1s[rg * 2 + 1][lr][ks * 32 + lk8];
        bf16x8 bn[4];
        const unsigned short* bk = bb1 + (((size_t)ks * 8) << 9);
#pragma unroll
        for (int n = 0; n < 4; n++) bn[n] = *(const bf16x8*)(bk + ((size_t)n << 9));
#pragma unroll
        for (int n = 0; n < 4; n++) {
            acc2[0][n] = __builtin_amdgcn_mfma_f32_16x16x32_bf16(af0, bn[n], acc2[0][n], 0, 0, 0);
            acc2[1][n] = __builtin_amdgcn_mfma_f32_16x16x32_bf16(af1, bn[n], acc2[1][n], 0, 0, 0);
        }
    }

    const int cbase = ch * 64 + lr * 4;
    float4 b4 = *(const float4*)(bf1 + cbase);
    float bv[4] = {b4.x, b4.y, b4.z, b4.w};
#pragma unroll
    for (int t = 0; t < 2; t++) {
        int row0 = (tile0 + t) * 16;
#pragma unroll
        for (int j = 0; j < 4; j++) {
            int row = row0 + rbase + j;
            if (row < M) {
                ushort4 o;
                o.x = f2bf(fast_tanh(acc2[t][0][j] + bv[0]));
                o.y = f2bf(fast_tanh(acc2[t][1][j] + bv[1]));
                o.z = f2bf(fast_tanh(acc2[t][2][j] + bv[2]));
                o.w = f2bf(fast_tanh(acc2[t][3][j] + bv[3]));
                *(ushort4*)(x_bf + ((size_t)row << 7) + cbase) = o;
            }
        }
    }
}

// ============ MFMA K=128 single-tile, fragment-major B, fused epilogue (s4) ============
template<bool ABF16, bool TANH, bool L2, bool RESID, bool AUX, bool AUXBF,
         bool F32OUT, bool BF16OUT, bool BIAS>
__global__ __launch_bounds__(256, 4)
void mfma_ep(const void* __restrict__ A_, const unsigned short* __restrict__ Wt,
             const float* __restrict__ bias, const unsigned short* __restrict__ resid_bf,
             const void* __restrict__ aux_in, float* __restrict__ aux_out,
             float* __restrict__ out, unsigned short* __restrict__ out_bf, int M)
{
    const int tid  = threadIdx.x;
    const int row0 = blockIdx.x * 64;
    const int wv   = tid >> 6, lane = tid & 63;
    const int lr   = lane & 15;
    const int lk8  = (lane >> 4) * 8;
    const int wr   = wv * 16;

    const unsigned short* Abr;
    const float*          Afr;
    {
        int r = row0 + wr + lr;
        r = r < M ? r : (M - 1);
        Abr = (const unsigned short*)A_ + ((size_t)r << 7) + lk8;
        Afr = (const float*)A_          + ((size_t)r << 7) + lk8;
    }
    const unsigned short* wb = Wt + (lane << 3);

    f32x4 acc[8];
#pragma unroll
    for (int n = 0; n < 8; n++)
#pragma unroll
        for (int j = 0; j < 4; j++) acc[n][j] = 0.f;

#pragma unroll 2
    for (int ks = 0; ks < 4; ks++) {
        bf16x8 af, bn[8];
        if (ABF16) af = *(const bf16x8*)(Abr + ks * 32);
        else {
            float4 a = *(const float4*)(Afr + ks * 32);
            float4 b = *(const float4*)(Afr + ks * 32 + 4);
            af[0]=(short)f2bf(a.x); af[1]=(short)f2bf(a.y); af[2]=(short)f2bf(a.z); af[3]=(short)f2bf(a.w);
            af[4]=(short)f2bf(b.x); af[5]=(short)f2bf(b.y); af[6]=(short)f2bf(b.z); af[7]=(short)f2bf(b.w);
        }
#pragma unroll
        for (int n = 0; n < 8; n++)
            bn[n] = *(const bf16x8*)(wb + ((((ks << 3) + n)) << 9));
#pragma unroll
        for (int n = 0; n < 8; n++)
            acc[n] = __builtin_amdgcn_mfma_f32_16x16x32_bf16(af, bn[n], acc[n], 0, 0, 0);
    }

    const int cbase = lr * 8;
    float bv[8];
    if (BIAS) {
        float4 b0 = *(const float4*)(bias + cbase);
        float4 b1 = *(const float4*)(bias + cbase + 4);
        bv[0]=b0.x; bv[1]=b0.y; bv[2]=b0.z; bv[3]=b0.w;
        bv[4]=b1.x; bv[5]=b1.y; bv[6]=b1.z; bv[7]=b1.w;
    } else {
#pragma unroll
        for (int n = 0; n < 8; n++) bv[n] = 0.f;
    }
    const int rbase = (lane >> 4) * 4;

#pragma unroll
    for (int j = 0; j < 4; j++) {
        int row = row0 + wr + rbase + j;
        bool ok = row < M;
        size_t base = ((size_t)row << 7) + cbase;
        float v[8];
#pragma unroll
        for (int n = 0; n < 8; n++) {
            v[n] = acc[n][j] + bv[n];
            if (TANH) v[n] = fast_tanh(v[n]);
        }
        if (RESID) {
            if (ok) {
                bf16x8 rv = *(const bf16x8*)(resid_bf + base);
#pragma unroll
                for (int n = 0; n < 8; n++) v[n] += bf2f((unsigned short)rv[n]);
            }
        }
        if (L2) {
            float s = 0.f;
#pragma unroll
            for (int n = 0; n < 8; n++) s += v[n] * v[n];
#pragma unroll
            for (int msk = 8; msk >= 1; msk >>= 1) s += __shfl_xor(s, msk);
            float sc = 1.f / fmaxf(sqrtf(s), 1e-12f);
#pragma unroll
            for (int n = 0; n < 8; n++) v[n] *= sc;
        }
        if (ok) {
            if (F32OUT) {
                *(float4*)(out + base)     = make_float4(v[0], v[1], v[2], v[3]);
                *(float4*)(out + base + 4) = make_float4(v[4], v[5], v[6], v[7]);
            }
            if (BF16OUT) {
                bf16x8 o;
#pragma unroll
                for (int n = 0; n < 8; n++) o[n] = (short)f2bf(v[n]);
                *(bf16x8*)(out_bf + base) = o;
            }
            if (AUX) {
                float ai[8];
                if (AUXBF) {
                    bf16x8 av = *(const bf16x8*)((const unsigned short*)aux_in + base);
#pragma unroll
                    for (int n = 0; n < 8; n++) ai[n] = bf2f((unsigned short)av[n]);
                } else {
                    float4 a0 = *(const float4*)((const float*)aux_in + base);
                    float4 a1 = *(const float4*)((const float*)aux_in + base + 4);
                    ai[0]=a0.x; ai[1]=a0.y; ai[2]=a0.z; ai[3]=a0.w;
                    ai[4]=a1.x; ai[5]=a1.y; ai[6]=a1.z; ai[7]=a1.w;
                }
                *(float4*)(aux_out + base)     = make_float4(ai[0]+v[0], ai[1]+v[1], ai[2]+v[2], ai[3]+v[3]);
                *(float4*)(aux_out + base + 4) = make_float4(ai[4]+v[4], ai[5]+v[5], ai[6]+v[6], ai[7]+v[7]);
            }
        }
    }
}

// ============ fused tail (fragment-major weights) ============
__global__ __launch_bounds__(256, 4)
void tail_fused(const unsigned short* __restrict__ h_bf, const float* __restrict__ accf,
                const unsigned short* __restrict__ Wt7,
                const float* __restrict__ bemb, const float* __restrict__ bl,
                const float* __restrict__ br,
                float* __restrict__ embO, float* __restrict__ lftO,
                float* __restrict__ rgtO, int M)
{
    __shared__ __align__(16) unsigned short ldsA[4][16][136];
    __shared__ __align__(16) unsigned short ldsB[4][16][136];

    const int tid = threadIdx.x;
    const int wv = tid >> 6, lane = tid & 63;
    const int lr = lane & 15;
    const int lk8 = (lane >> 4) * 8;
    const int rbase = (lane >> 4) * 4;
    const int row0 = blockIdx.x * 64 + wv * 16;
    const int cbase = lr * 8;

    const unsigned short* Wg1t  = Wt7 + 1 * 16384 + (lane << 3);
    const unsigned short* Wembt = Wt7 + 2 * 16384 + (lane << 3);
    const unsigned short* Wl0t  = Wt7 + 3 * 16384 + (lane << 3);
    const unsigned short* Wl1t  = Wt7 + 4 * 16384 + (lane << 3);
    const unsigned short* Wr0t  = Wt7 + 5 * 16384 + (lane << 3);
    const unsigned short* Wr1t  = Wt7 + 6 * 16384 + (lane << 3);

    f32x4 acc[8];

#define ZACC() { _Pragma("unroll") for (int n = 0; n < 8; n++) \
                 _Pragma("unroll") for (int q = 0; q < 4; q++) acc[n][q] = 0.f; }
#define MM128(AFRAG, WPTR)                                                            \
    _Pragma("unroll")                                                                 \
    for (int ks = 0; ks < 4; ks++) {                                                  \
        bf16x8 af = (AFRAG);                                                          \
        bf16x8 bn[8];                                                                 \
        _Pragma("unroll")                                                             \
        for (int n = 0; n < 8; n++)                                                   \
            bn[n] = *(const bf16x8*)((WPTR) + ((((ks << 3) + n)) << 9));              \
        _Pragma("unroll")                                                             \
        for (int n = 0; n < 8; n++)                                                   \
            acc[n] = __builtin_amdgcn_mfma_f32_16x16x32_bf16(af, bn[n], acc[n], 0, 0, 0); \
    }
#define LDBIAS(BV, P) { float4 b0_ = *(const float4*)((P) + cbase);                   \
                        float4 b1_ = *(const float4*)((P) + cbase + 4);               \
                        BV[0]=b0_.x; BV[1]=b0_.y; BV[2]=b0_.z; BV[3]=b0_.w;           \
                        BV[4]=b1_.x; BV[5]=b1_.y; BV[6]=b1_.z; BV[7]=b1_.w; }
#define L2NORM(V) { float s_ = 0.f;                                                   \
                    _Pragma("unroll") for (int n = 0; n < 8; n++) s_ += V[n]*V[n];    \
                    _Pragma("unroll") for (int mk = 8; mk >= 1; mk >>= 1) s_ += __shfl_xor(s_, mk); \
                    float sc_ = 1.f / fmaxf(sqrtf(s_), 1e-12f);                       \
                    _Pragma("unroll") for (int n = 0; n < 8; n++) V[n] *= sc_; }

    // ---- stage 1: n1 = l2norm(tanh(h @ Wg1)); acc = accf + n1 ----
    const unsigned short* hrow;
    {
        int r = row0 + lr;
        r = r < M ? r : (M - 1);
        hrow = h_bf + ((size_t)r << 7) + lk8;
    }
    ZACC();
    MM128(*(const bf16x8*)(hrow + ks * 32), Wg1t);
#pragma unroll
    for (int j = 0; j < 4; j++) {
        int row = row0 + rbase + j;
        int rc = row < M ? row : (M - 1);
        float v[8];
#pragma unroll
        for (int n = 0; n < 8; n++) v[n] = fast_tanh(acc[n][j]);
        L2NORM(v);
        bf16x8 o;
#pragma unroll
        for (int n = 0; n < 8; n++) o[n] = (short)f2bf(v[n]);
        *(bf16x8*)&ldsA[wv][rbase + j][cbase] = o;
        float4 a0 = *(const float4*)(accf + ((size_t)rc << 7) + cbase);
        float4 a1 = *(const float4*)(accf + ((size_t)rc << 7) + cbase + 4);
        float av[8] = {a0.x+v[0], a0.y+v[1], a0.z+v[2], a0.w+v[3],
                       a1.x+v[4], a1.y+v[5], a1.z+v[6], a1.w+v[7]};
        bf16x8 ob;
#pragma unroll
        for (int n = 0; n < 8; n++) ob[n] = (short)f2bf(av[n]);
        *(bf16x8*)&ldsB[wv][rbase + j][cbase] = ob;
    }

    // ---- stage 2: emb = l2norm(acc @ Wemb + bemb) ----
    ZACC();
    MM128(*(const bf16x8*)&ldsB[wv][lr][ks * 32 + lk8], Wembt);
    {
        float bv[8]; LDBIAS(bv, bemb);
#pragma unroll
        for (int j = 0; j < 4; j++) {
            int row = row0 + rbase + j;
            float v[8];
#pragma unroll
            for (int n = 0; n < 8; n++) v[n] = acc[n][j] + bv[n];
            L2NORM(v);
            if (row < M) {
                size_t base = ((size_t)row << 7) + cbase;
                *(float4*)(embO + base)     = make_float4(v[0], v[1], v[2], v[3]);
                *(float4*)(embO + base + 4) = make_float4(v[4], v[5], v[6], v[7]);
            }
        }
    }

    // ---- stage 3: lft0 = tanh(n1 @ Wl0 + bl0) + n1 ----
    ZACC();
    MM128(*(const bf16x8*)&ldsA[wv][lr][ks * 32 + lk8], Wl0t);
    {
        float bv[8]; LDBIAS(bv, bl);
#pragma unroll
        for (int j = 0; j < 4; j++) {
            bf16x8 rv = *(const bf16x8*)&ldsA[wv][rbase + j][cbase];
            bf16x8 ob;
#pragma unroll
            for (int n = 0; n < 8; n++)
                ob[n] = (short)f2bf(fast_tanh(acc[n][j] + bv[n]) + bf2f((unsigned short)rv[n]));
            *(bf16x8*)&ldsB[wv][rbase + j][cbase] = ob;
        }
    }

    // ---- stage 4: lft = tanh(lft0 @ Wl1 + bl1) ----
    ZACC();
    MM128(*(const bf16x8*)&ldsB[wv][lr][ks * 32 + lk8], Wl1t);
    {
        float bv[8]; LDBIAS(bv, bl + 128);
#pragma unroll
        for (int j = 0; j < 4; j++) {
            int row = row0 + rbase + j;
            if (row < M) {
                size_t base = ((size_t)row << 7) + cbase;
                *(float4*)(lftO + base)     = make_float4(fast_tanh(acc[0][j]+bv[0]), fast_tanh(acc[1][j]+bv[1]),
                                                          fast_tanh(acc[2][j]+bv[2]), fast_tanh(acc[3][j]+bv[3]));
                *(float4*)(lftO + base + 4) = make_float4(fast_tanh(acc[4][j]+bv[4]), fast_tanh(acc[5][j]+bv[5]),
                                                          fast_tanh(acc[6][j]+bv[6]), fast_tanh(acc[7][j]+bv[7]));
            }
        }
    }

    // ---- stage 5: rgt0 = tanh(n1 @ Wr0 + br0) + n1 ----
    ZACC();
    MM128(*(const bf16x8*)&ldsA[wv][lr][ks * 32 + lk8], Wr0t);
    {
        float bv[8]; LDBIAS(bv, br);
#pragma unroll
        for (int j = 0; j < 4; j++) {
            bf16x8 rv = *(const bf16x8*)&ldsA[wv][rbase + j][cbase];
            bf16x8 ob;
#pragma unroll
            for (int n = 0; n < 8; n++)
                ob[n] = (short)f2bf(fast_tanh(acc[n][j] + bv[n]) + bf2f((unsigned short)rv[n]));
            *(bf16x8*)&ldsB[wv][rbase + j][cbase] = ob;
        }
    }

    // ---- stage 6: rgt = tanh(rgt0 @ Wr1 + br1) ----
    ZACC();
    MM128(*(const bf16x8*)&ldsB[wv][lr][ks * 32 + lk8], Wr1t);
    {
        float bv[8]; LDBIAS(bv, br + 128);
#pragma unroll
        for (int j = 0; j < 4; j++) {
            int row = row0 + rbase + j;
            if (row < M) {
                size_t base = ((size_t)row << 7) + cbase;
                *(float4*)(rgtO + base)     = make_float4(fast_tanh(acc[0][j]+bv[0]), fast_tanh(acc[1][j]+bv[1]),
                                                          fast_tanh(acc[2][j]+bv[2]), fast_tanh(acc[3][j]+bv[3]));
                *(float4*)(rgtO + base + 4) = make_float4(fast_tanh(acc[4][j]+bv[4]), fast_tanh(acc[5][j]+bv[5]),
                                                          fast_tanh(acc[6][j]+bv[6]), fast_tanh(acc[7][j]+bv[7]));
            }
        }
    }
#undef ZACC
#undef MM128
#undef LDBIAS
#undef L2NORM
}

// ============ bucketed CSR build ============
#define RCHUNK 16384

__global__ __launch_bounds__(256)
void bhist_k(const int* __restrict__ rows, int* __restrict__ bcnt, int E, int NB)
{
    __shared__ int lc[1024];
    for (int b = threadIdx.x; b < NB; b += 256) lc[b] = 0;
    __syncthreads();
    int start = blockIdx.x * RCHUNK;
    int end = min(start + RCHUNK, E);
    for (int i = start + threadIdx.x; i < end; i += 256)
        atomicAdd(&lc[rows[i] >> 7], 1);
    __syncthreads();
    for (int b = threadIdx.x; b < NB; b += 256)
        if (lc[b]) atomicAdd(&bcnt[b], lc[b]);
}

__global__ __launch_bounds__(256)
void bucket_scan(const int* __restrict__ bcnt, int* __restrict__ bbase,
                 int* __restrict__ bcur, int NB)
{
    __shared__ int sdata[256];
    const int tid = threadIdx.x;
    int loc[4]; int s = 0;
#pragma unroll
    for (int j = 0; j < 4; j++) {
        int i = tid * 4 + j;
        int v = (i < NB) ? bcnt[i] : 0;
        loc[j] = s; s += v;
    }
    sdata[tid] = s;
    __syncthreads();
    int x = s;
    for (int off = 1; off < 256; off <<= 1) {
        int t = 0;
        if (tid >= off) t = sdata[tid - off];
        __syncthreads();
        x += t;
        sdata[tid] = x;
        __syncthreads();
    }
    int excl = x - s;
#pragma unroll
    for (int j = 0; j < 4; j++) {
        int i = tid * 4 + j;
        if (i < NB) { bbase[i] = excl + loc[j]; bcur[i] = excl + loc[j]; }
    }
    if (tid == 255) bbase[NB] = x;
}

__global__ __launch_bounds__(256)
void bucket_scatter(const int* __restrict__ rows, const int* __restrict__ cols,
                    const float* __restrict__ vals, int* __restrict__ bcur,
                    int2* __restrict__ tmp, int E, int NB)
{
    __shared__ int lcnt[1024];
    __shared__ int lbase[1024];
    for (int b = threadIdx.x; b < NB; b += 256) lcnt[b] = 0;
    __syncthreads();
    int start = blockIdx.x * RCHUNK;
    int end = min(start + RCHUNK, E);
    for (int i = start + threadIdx.x; i < end; i += 256)
        atomicAdd(&lcnt[rows[i] >> 7], 1);
    __syncthreads();
    for (int b = threadIdx.x; b < NB; b += 256) {
        int c = lcnt[b];
        lbase[b] = c ? atomicAdd(&bcur[b], c) : 0;
        lcnt[b] = 0;
    }
    __syncthreads();
    for (int i = start + threadIdx.x; i < end; i += 256) {
        int r = rows[i];
        int b = r >> 7;
        int off = atomicAdd(&lcnt[b], 1);
        tmp[lbase[b] + off] = make_int2(cols[i] | ((r & 127) << 17), __float_as_int(vals[i]));
    }
}

__global__ __launch_bounds__(256)
void csr_place(const int2* __restrict__ tmp, const int* __restrict__ bbase,
               int* __restrict__ rowptr, int2* __restrict__ packed, int M, int NB)
{
    __shared__ int lcnt[128];
    __shared__ int lofs[128];
    const int tid = threadIdx.x;
    const int b = blockIdx.x;
    const int s = bbase[b], e = bbase[b + 1];
    const int rb = b << 7;
    if (tid < 128) lcnt[tid] = 0;
    __syncthreads();
    for (int i = s + tid; i < e; i += 256)
        atomicAdd(&lcnt[(((unsigned)tmp[i].x) >> 17) & 127], 1);
    __syncthreads();
    if (tid == 0) {
        int run = s;
#pragma unroll 8
        for (int r = 0; r < 128; r++) { lofs[r] = run; run += lcnt[r]; }
    }
    __syncthreads();
    if (tid < 128 && rb + tid < M) rowptr[rb + tid] = lofs[tid];
    if (b == NB - 1 && tid == 0) rowptr[M] = e;
    if (tid < 128) lcnt[tid] = 0;
    __syncthreads();
    for (int i = s + tid; i < e; i += 256) {
        int2 t = tmp[i];
        int rl = (((unsigned)t.x) >> 17) & 127;
        int pos = lofs[rl] + atomicAdd(&lcnt[rl], 1);
        packed[pos] = make_int2(t.x & 0x1FFFF, t.y);
    }
}

// ============ CSR SpMM: 16 lanes/edge x 4 edge-groups, 16B gathers ============
__global__ __launch_bounds__(256)
void spmm_csr(const int* __restrict__ rowptr, const int2* __restrict__ packed,
              const unsigned short* __restrict__ embb, unsigned short* __restrict__ hb, int N)
{
    const int wv = threadIdx.x >> 6, lane = threadIdx.x & 63;
    const int g = lane >> 4, q = lane & 15;
    const int r = blockIdx.x * 4 + wv;
    if (r >= N) return;
    const int s = rowptr[r], e = rowptr[r + 1];
    const unsigned short* __restrict__ eb = embb + q * 8;

    float a0=0.f,a1=0.f,a2=0.f,a3=0.f,a4=0.f,a5=0.f,a6=0.f,a7=0.f;
    int i = s + g;
    for (; i + 12 < e; i += 16) {
#pragma unroll
        for (int u = 0; u < 4; u++) {
            int2 p = packed[i + 4 * u];
            uint4 m = *(const uint4*)(eb + ((size_t)p.x << 7));
            float v = __int_as_float(p.y);
            a0 += v * __uint_as_float(m.x << 16);
            a1 += v * __uint_as_float(m.x & 0xffff0000u);
            a2 += v * __uint_as_float(m.y << 16);
            a3 += v * __uint_as_float(m.y & 0xffff0000u);
            a4 += v * __uint_as_float(m.z << 16);
            a5 += v * __uint_as_float(m.z & 0xffff0000u);
            a6 += v * __uint_as_float(m.w << 16);
            a7 += v * __uint_as_float(m.w & 0xffff0000u);
        }
    }
    for (; i < e; i += 4) {
        int2 p = packed[i];
        uint4 m = *(const uint4*)(eb + ((size_t)p.x << 7));
        float v = __int_as_float(p.y);
        a0 += v * __uint_as_float(m.x << 16);
        a1 += v * __uint_as_float(m.x & 0xffff0000u);
        a2 += v * __uint_as_float(m.y << 16);
        a3 += v * __uint_as_float(m.y & 0xffff0000u);
        a4 += v * __uint_as_float(m.z << 16);
        a5 += v * __uint_as_float(m.z & 0xffff0000u);
        a6 += v * __uint_as_float(m.w << 16);
        a7 += v * __uint_as_float(m.w & 0xffff0000u);
    }
#pragma unroll
    for (int msk = 16; msk <= 32; msk <<= 1) {
        a0 += __shfl_xor(a0, msk); a1 += __shfl_xor(a1, msk);
        a2 += __shfl_xor(a2, msk); a3 += __shfl_xor(a3, msk);
        a4 += __shfl_xor(a4, msk); a5 += __shfl_xor(a5, msk);
        a6 += __shfl_xor(a6, msk); a7 += __shfl_xor(a7, msk);
    }
    if (g == 0) {
        unsigned o0 = (unsigned)f2bf(a0) | ((unsigned)f2bf(a1) << 16);
        unsigned o1 = (unsigned)f2bf(a2) | ((unsigned)f2bf(a3) << 16);
        unsigned o2 = (unsigned)f2bf(a4) | ((unsigned)f2bf(a5) << 16);
        unsigned o3 = (unsigned)f2bf(a6) | ((unsigned)f2bf(a7) << 16);
        *(uint4*)(hb + ((size_t)r << 7) + q * 8) = make_uint4(o0, o1, o2, o3);
    }
}

// ============ launch ============
extern "C" void kernel_launch(void* const* d_in, const int* in_sizes, int n_in,
                              void* d_out, int out_size, void* d_ws, size_t ws_size,
                              hipStream_t stream)
{
    const float* feat  = (const float*)d_in[0];
    const int*   srows = (const int*)  d_in[1];
    const int*   scols = (const int*)  d_in[2];
    const float* svals = (const float*)d_in[3];
    const float* Wf0   = (const float*)d_in[4];
    const float* bf0   = (const float*)d_in[5];
    const float* Wf1   = (const float*)d_in[6];
    const float* bf1   = (const float*)d_in[7];
    const float* Wg    = (const float*)d_in[8];
    const float* Wemb  = (const float*)d_in[9];
    const float* bemb  = (const float*)d_in[10];
    const float* Wl    = (const float*)d_in[11];
    const float* bl    = (const float*)d_in[12];
    const float* Wr    = (const float*)d_in[13];
    const float* br    = (const float*)d_in[14];

    const int M = in_sizes[0] / 512;   // 100000 nodes
    const int E = in_sizes[1];         // 3200000 edges
    const int NB = (M + 127) >> 7;     // 782 buckets
    const int NT = (M + 15) >> 4;      // 6250 row-tiles

    float* out = (float*)d_out;
    float* R0 = out;
    float* R1 = out + (size_t)M * 128;
    float* R2 = out + (size_t)M * 256;

    // ---- ws layout ----
    float* ws = (float*)d_ws;
    float* accf = ws;
    int2*  tmp  = (int2*)ws;
    int*   ip = (int*)(ws + (size_t)M * 128);
    int*   rowptr  = ip;
    int2*  packed  = (int2*)(ip + (((size_t)M + 4) & ~(size_t)3));
    int*   bcnt    = (int*)(packed + E);
    int*   bbase   = bcnt + 1024;
    int*   bcur    = bbase + 1032;
    unsigned short* h_ws = (unsigned short*)(bcur + 1024);
    unsigned short* Wt0  = h_ws + (size_t)M * 128;
    unsigned short* Wt1  = Wt0 + 256 * 512;
    unsigned short* Wt7  = Wt1 + 128 * 256;

    // ---- d_out scratch timeline ----
    unsigned short* R1a = (unsigned short*)R1;
    unsigned short* featA = (unsigned short*)R0;   // [NT*8192] bf16 A'-layout
    unsigned short* x_bf  = (unsigned short*)R2;
    unsigned short* n0_bf = R1a;

    dim3 blk(256);
    const int gm64  = (M + 63) / 64;
    const int gm128 = (M + 127) / 128;
    const int nch   = (E + RCHUNK - 1) / RCHUNK;
    const int nchunks = NT * 1024;

    // weight converts
    wconvD<<<(512*256 + 255)/256, blk, 0, stream>>>(Wf0, Wt0, 512, 256);
    wconvD<<<(256*128 + 255)/256, blk, 0, stream>>>(Wf1, Wt1, 256, 128);
    wconv7<<<(7*16384 + 255)/256, blk, 0, stream>>>(Wg, Wemb, Wl, Wr, Wt7);

    // feat -> bf16 A'-layout
    f32_to_bf16A<<<(nchunks + 255)/256, blk, 0, stream>>>(feat, featA, nchunks);

    // ---- CSR build ----
    hipMemsetAsync(bcnt, 0, (size_t)NB * 4, stream);
    bhist_k<<<nch, blk, 0, stream>>>(srows, bcnt, E, NB);
    bucket_scan<<<1, blk, 0, stream>>>(bcnt, bbase, bcur, NB);
    bucket_scatter<<<nch, blk, 0, stream>>>(srows, scols, svals, bcur, tmp, E, NB);
    csr_place<<<NB, blk, 0, stream>>>(tmp, bbase, rowptr, packed, M, NB);

    // ---- network ----
    mfma_head<<<gm128, dim3(512), 0, stream>>>(featA, Wt0, bf0, Wt1, bf1, x_bf, M);
    spmm_csr<<<(M + 3) / 4, blk, 0, stream>>>(rowptr, packed, x_bf, h_ws, M);
    mfma_ep<true,true,true,false,true,true,false,true,false><<<gm64,blk,0,stream>>>(
        h_ws, Wt7, nullptr, nullptr, x_bf, accf, nullptr, n0_bf, M);
    spmm_csr<<<(M + 3) / 4, blk, 0, stream>>>(rowptr, packed, n0_bf, h_ws, M);
    tail_fused<<<gm64, blk, 0, stream>>>(h_ws, accf, Wt7, bemb, bl, br, R0, R1, R2, M);
}